// Round 9
// baseline (1184.174 us; speedup 1.0000x reference)
//
#include <hip/hip_runtime.h>
#include <math.h>

#define N_NODES 50000
#define N_EDGES 400000
#define DIM_IN  128
#define H       128
#define E_DIM   16
#define NLAYERS 3

#define K1      272        // 2H + E_DIM
#define K1P     288        // padded to multiple of 32
#define AS      296        // edge A-tile row stride (shorts)
#define HS      136        // hid/m tile row stride (shorts)
#define US      264        // update A-tile row stride (shorts)
#define PS      136        // proj A-tile row stride (shorts)
#define MB      32         // rows per proj tile
#define EMB     64         // rows per edge tile
#define UMB     64         // rows per update block
#define TILE_C  32         // edge-slot window for node-aligned tiles
#define NTILES  (N_EDGES / TILE_C)   // 12500

typedef short  s16x8 __attribute__((ext_vector_type(8)));
typedef float  f32x4 __attribute__((ext_vector_type(4)));

__device__ inline unsigned short f2bf(float f) {
    union { float f; unsigned u; } v; v.f = f;
    unsigned r = v.u + 0x7FFFu + ((v.u >> 16) & 1u);
    return (unsigned short)(r >> 16);
}
__device__ inline float bf2f(unsigned short u) {
    union { unsigned u; float f; } v; v.u = (unsigned)u << 16; return v.f;
}

// ---------------------------------------------------------------------------
// weight convert/transpose kernels (tiny, once per launch)
// ---------------------------------------------------------------------------
__global__ __launch_bounds__(256)
void convert_w1(const float* __restrict__ W1, unsigned short* __restrict__ W1t)
{   // [L][272][128] f32 -> [L][128][288] bf16 (zero pad)
    const int o = blockIdx.x * 256 + threadIdx.x;
    const int l = o / (128 * K1P);
    const int r = o % (128 * K1P);
    const int n = r / K1P;
    const int k = r % K1P;
    const float v = (k < K1) ? W1[(size_t)l * K1 * H + (size_t)k * H + n] : 0.f;
    W1t[o] = f2bf(v);
}

__global__ __launch_bounds__(256)
void convert_w2(const float* __restrict__ W2, unsigned short* __restrict__ W2t)
{   // [L][128][128] -> transposed bf16
    const int o = blockIdx.x * 256 + threadIdx.x;
    const int l = o / (H * H);
    const int r = o % (H * H);
    const int n = r / H;
    const int k = r % H;
    W2t[o] = f2bf(W2[(size_t)l * H * H + (size_t)k * H + n]);
}

__global__ __launch_bounds__(256)
void convert_wu(const float* __restrict__ Wu, unsigned short* __restrict__ Wut)
{   // [L][256][128] -> [L][128][256] bf16
    const int o = blockIdx.x * 256 + threadIdx.x;
    const int l = o / (H * 256);
    const int r = o % (H * 256);
    const int n = r / 256;
    const int k = r % 256;
    Wut[o] = f2bf(Wu[(size_t)l * 256 * H + (size_t)k * H + n]);
}

__global__ __launch_bounds__(256)
void convert_wp(const float* __restrict__ Wp, unsigned short* __restrict__ Wpt)
{   // [128][128] -> transposed bf16
    const int o = blockIdx.x * 256 + threadIdx.x;
    const int n = o / H;
    const int k = o % H;
    Wpt[o] = f2bf(Wp[(size_t)k * H + n]);
}

// edge_attr -> bf16 in sorted order
__global__ __launch_bounds__(256)
void convert_ea(const float* __restrict__ ea, const int* __restrict__ perm,
                unsigned short* __restrict__ eabf)
{
    const int o = blockIdx.x * 256 + threadIdx.x;
    const int p = o >> 3;
    const int j = (o & 7) * 2;
    const int pe = perm[p];
    const float2 v = *(const float2*)&ea[(size_t)pe * E_DIM + j];
    eabf[(size_t)p * E_DIM + j]     = f2bf(v.x);
    eabf[(size_t)p * E_DIM + j + 1] = f2bf(v.y);
}

// ---------------------------------------------------------------------------
// counting sort of edges by destination (i_idx) + CSR offsets
// ---------------------------------------------------------------------------
__global__ __launch_bounds__(256)
void hist_kernel(const int* __restrict__ ei, int* __restrict__ hist)
{
    const int e = blockIdx.x * 256 + threadIdx.x;
    if (e < N_EDGES) atomicAdd(&hist[ei[e]], 1);
}

__global__ __launch_bounds__(256)
void scan_kernel(const int* __restrict__ hist, int* __restrict__ cursor,
                 int* __restrict__ node_start)
{
    __shared__ int ps[256];
    const int t = threadIdx.x;
    const int CH = 196;
    const int base = t * CH;
    int s = 0;
    for (int i = 0; i < CH; ++i) { const int idx = base + i; if (idx < N_NODES) s += hist[idx]; }
    ps[t] = s; __syncthreads();
    for (int off = 1; off < 256; off <<= 1) {
        const int v = (t >= off) ? ps[t - off] : 0;
        __syncthreads();
        ps[t] += v;
        __syncthreads();
    }
    int run = (t > 0) ? ps[t - 1] : 0;
    for (int i = 0; i < CH; ++i) {
        const int idx = base + i;
        if (idx < N_NODES) { cursor[idx] = run; node_start[idx] = run; run += hist[idx]; }
    }
    if (t == 255) node_start[N_NODES] = N_EDGES;
}

__global__ __launch_bounds__(256)
void scatter_kernel(const int* __restrict__ ei, int* __restrict__ cursor,
                    int* __restrict__ i_s, int* __restrict__ j_s, int* __restrict__ perm)
{
    const int e = blockIdx.x * 256 + threadIdx.x;
    if (e < N_EDGES) {
        const int d = ei[e];
        const int p = atomicAdd(&cursor[d], 1);
        i_s[p] = d;
        j_s[p] = ei[N_EDGES + e];
        perm[p] = e;
    }
}

// node-aligned tile bounds: tile t owns nodes with node_start in [32t, 32t+32)
__global__ __launch_bounds__(256)
void tile_bounds(const int* __restrict__ node_start,
                 int* __restrict__ t_ns, int* __restrict__ t_es)
{
    const int t = blockIdx.x * 256 + threadIdx.x;
    if (t > NTILES) return;
    const int target = t * TILE_C;          // == N_EDGES at t == NTILES
    int lo = 0, hi = N_NODES;
    while (lo < hi) {
        const int mid = (lo + hi) >> 1;
        if (node_start[mid] < target) lo = mid + 1; else hi = mid;
    }
    t_ns[t] = lo;
    t_es[t] = node_start[lo];               // node_start[N]=E covers lo==N
}

// ---------------------------------------------------------------------------
// proj (MFMA): hbf = bf16(x @ Wp + b)
// ---------------------------------------------------------------------------
__global__ __launch_bounds__(256)
void proj_mfma(const float* __restrict__ x, const unsigned short* __restrict__ Wpt,
               const float* __restrict__ b, unsigned short* __restrict__ hbf)
{
    __shared__ __align__(16) unsigned short A[MB][PS];
    const int tid = threadIdx.x;
    const int n0 = blockIdx.x * MB;
    const int wave = tid >> 6, lane = tid & 63, l15 = lane & 15, l4 = lane >> 4;
    const int colbase = wave * 32;

#pragma unroll
    for (int i = 0; i < 4; ++i) {
        const int f = tid + i * 256;
        const int row = f >> 5, c4 = f & 31;
        const int node = min(n0 + row, N_NODES - 1);
        const float4 v = *((const float4*)(x + (size_t)node * DIM_IN) + c4);
        unsigned short o[4] = { f2bf(v.x), f2bf(v.y), f2bf(v.z), f2bf(v.w) };
        *(uint2*)&A[row][c4 * 4] = *(const uint2*)o;
    }
    __syncthreads();

    f32x4 acc[2][2];
#pragma unroll
    for (int mt = 0; mt < 2; ++mt)
#pragma unroll
        for (int nt = 0; nt < 2; ++nt) acc[mt][nt] = (f32x4)0.f;

    for (int k = 0; k < DIM_IN; k += 32) {
        const s16x8 a0 = *(const s16x8*)&A[l15][k + l4 * 8];
        const s16x8 a1 = *(const s16x8*)&A[16 + l15][k + l4 * 8];
        const s16x8 b0 = *(const s16x8*)&Wpt[(size_t)(colbase + l15) * DIM_IN + k + l4 * 8];
        const s16x8 b1 = *(const s16x8*)&Wpt[(size_t)(colbase + 16 + l15) * DIM_IN + k + l4 * 8];
        acc[0][0] = __builtin_amdgcn_mfma_f32_16x16x32_bf16(a0, b0, acc[0][0], 0, 0, 0);
        acc[0][1] = __builtin_amdgcn_mfma_f32_16x16x32_bf16(a0, b1, acc[0][1], 0, 0, 0);
        acc[1][0] = __builtin_amdgcn_mfma_f32_16x16x32_bf16(a1, b0, acc[1][0], 0, 0, 0);
        acc[1][1] = __builtin_amdgcn_mfma_f32_16x16x32_bf16(a1, b1, acc[1][1], 0, 0, 0);
    }

    const float bi0 = b[colbase + l15], bi1 = b[colbase + 16 + l15];
#pragma unroll
    for (int mt = 0; mt < 2; ++mt)
#pragma unroll
        for (int r = 0; r < 4; ++r) {
            const int row = mt * 16 + l4 * 4 + r;
            const int n = n0 + row;
            if (n < N_NODES) {
                hbf[(size_t)n * H + colbase + l15]      = f2bf(acc[mt][0][r] + bi0);
                hbf[(size_t)n * H + colbase + 16 + l15] = f2bf(acc[mt][1][r] + bi1);
            }
        }
}

// ---------------------------------------------------------------------------
// edge message MLP: node-aligned tiles (exclusive node ownership) -> complete
// per-node sums -> plain bf16 stores. NO ATOMICS. Persistent blocks,
// 2 barriers/tile, register prefetch + register weights.
// ---------------------------------------------------------------------------
__global__ __launch_bounds__(256, 2)
void edge_kernel(const unsigned short* __restrict__ hbf,
                 const unsigned short* __restrict__ eabf,  // [E][16] bf16, sorted
                 const int*   __restrict__ i_s,
                 const int*   __restrict__ j_s,
                 const int*   __restrict__ t_ns,           // [NTILES+1]
                 const int*   __restrict__ t_es,           // [NTILES+1]
                 const unsigned short* __restrict__ W1t,   // [128][288]
                 const float* __restrict__ b1,
                 const unsigned short* __restrict__ W2t,   // [128][128]
                 const float* __restrict__ b2,
                 unsigned short* __restrict__ agg16)       // [N][128] bf16
{
    __shared__ __align__(16) unsigned short A[EMB][AS];     // 37888 B
    __shared__ __align__(16) unsigned short Hid[EMB * HS];  // 17408 B
    __shared__ __align__(16) unsigned short Mbf[EMB * HS];  // 17408 B
    __shared__ int idxbuf[2][EMB];                          //   512 B

    const int tid  = threadIdx.x;
    const int wave = tid >> 6;
    const int lane = tid & 63;
    const int l15  = lane & 15;
    const int l4   = lane >> 4;
    const int colbase = wave * 32;

    // gather role: thread covers (row = tid>>5 + 8i, c = tid&31), i=0..7
    const int ge_e = tid >> 5;
    const int ge_c = tid & 31;
    const int ge_ch = ge_c & 15;
    const int* __restrict__ gsel = (ge_c < 16) ? i_s : j_s;
    const int lds_off = (ge_c < 16 ? 0 : 128) + ge_ch * 8;

    // weights in registers (per wave: its 32 output cols)
    s16x8 w1f[2][9], w2f[2][4];
#pragma unroll
    for (int kt = 0; kt < 9; ++kt) {
        w1f[0][kt] = *(const s16x8*)&W1t[(size_t)(colbase + l15) * K1P + kt * 32 + l4 * 8];
        w1f[1][kt] = *(const s16x8*)&W1t[(size_t)(colbase + 16 + l15) * K1P + kt * 32 + l4 * 8];
    }
#pragma unroll
    for (int kt = 0; kt < 4; ++kt) {
        w2f[0][kt] = *(const s16x8*)&W2t[(size_t)(colbase + l15) * H + kt * 32 + l4 * 8];
        w2f[1][kt] = *(const s16x8*)&W2t[(size_t)(colbase + 16 + l15) * H + kt * 32 + l4 * 8];
    }
    const float b1c0 = b1[colbase + l15], b1c1 = b1[colbase + 16 + l15];
    const float b2c0 = b2[colbase + l15], b2c1 = b2[colbase + 16 + l15];

    int t = blockIdx.x;
    if (t >= NTILES) return;

    // ---- prologue: bounds + stage tile t
    int ts = t_ns[t];
    int es = t_es[t];
    int ee = t_es[t + 1];
    {
#pragma unroll
        for (int i = 0; i < 8; ++i) {
            const int ec = min(es + ge_e + i * 8, N_EDGES - 1);
            const int node = gsel[ec];
            const uint4 v = *((const uint4*)(hbf + (size_t)node * H) + ge_ch);
            *(uint4*)&A[ge_e + i * 8][lds_off] = v;
        }
        if (tid < 128) {
            const int e = min(es + (tid >> 1), N_EDGES - 1);
            const uint4 va = *(const uint4*)&eabf[(size_t)e * E_DIM + (tid & 1) * 8];
            *(uint4*)&A[tid >> 1][256 + (tid & 1) * 8] = va;
        } else {
            const int tt = tid - 128;
            const uint4 z = {0, 0, 0, 0};
            *(uint4*)&A[tt >> 1][272 + (tt & 1) * 8] = z;   // pad stays zero
        }
        if (tid < EMB) {
            const int e = es + tid;
            idxbuf[0][tid] = (e < ee) ? (i_s[e] - ts) : 127;
        }
    }
    __syncthreads();

    int p = 0;
    for (; t < NTILES; t += gridDim.x, p ^= 1) {
        const int t1 = t + gridDim.x;

        // ---- 1. prefetch next tile into registers
        uint4 pf[8];
        uint4 pfa = {0, 0, 0, 0};
        int   pfi = 0;
        int ts1 = 0, es1 = 0, ee1 = 0;
        if (t1 < NTILES) {
            ts1 = t_ns[t1]; es1 = t_es[t1]; ee1 = t_es[t1 + 1];
#pragma unroll
            for (int i = 0; i < 8; ++i) {
                const int ec = min(es1 + ge_e + i * 8, N_EDGES - 1);
                const int node = gsel[ec];
                pf[i] = *((const uint4*)(hbf + (size_t)node * H) + ge_ch);
            }
            if (tid < 128) {
                const int e = min(es1 + (tid >> 1), N_EDGES - 1);
                pfa = *(const uint4*)&eabf[(size_t)e * E_DIM + (tid & 1) * 8];
            }
            if (tid < EMB) {
                const int e = es1 + tid;
                pfi = (e < ee1) ? (i_s[e] - ts1) : 127;
            }
        }

        // ---- 2. GEMM1: A[64x288] x W1 -> acc
        f32x4 acc[4][2];
#pragma unroll
        for (int mt = 0; mt < 4; ++mt) { acc[mt][0] = (f32x4)0.f; acc[mt][1] = (f32x4)0.f; }

#pragma unroll
        for (int kt = 0; kt < 9; ++kt) {
#pragma unroll
            for (int mt = 0; mt < 4; ++mt) {
                const s16x8 a = *(const s16x8*)&A[mt * 16 + l15][kt * 32 + l4 * 8];
                acc[mt][0] = __builtin_amdgcn_mfma_f32_16x16x32_bf16(a, w1f[0][kt], acc[mt][0], 0, 0, 0);
                acc[mt][1] = __builtin_amdgcn_mfma_f32_16x16x32_bf16(a, w1f[1][kt], acc[mt][1], 0, 0, 0);
            }
        }

        // ---- 3. hid = relu(acc+b1) -> Hid
#pragma unroll
        for (int mt = 0; mt < 4; ++mt)
#pragma unroll
            for (int r = 0; r < 4; ++r) {
                const int row = mt * 16 + l4 * 4 + r;
                Hid[row * HS + colbase + l15]      = f2bf(fmaxf(acc[mt][0][r] + b1c0, 0.f));
                Hid[row * HS + colbase + 16 + l15] = f2bf(fmaxf(acc[mt][1][r] + b1c1, 0.f));
            }
        __syncthreads();             // barrier A: A reads done, Hid ready

        // ---- 4. drain prefetch into A / idxbuf[p^1]
        if (t1 < NTILES) {
#pragma unroll
            for (int i = 0; i < 8; ++i)
                *(uint4*)&A[ge_e + i * 8][lds_off] = pf[i];
            if (tid < 128)
                *(uint4*)&A[tid >> 1][256 + (tid & 1) * 8] = pfa;
            if (tid < EMB) idxbuf[p ^ 1][tid] = pfi;
        }

        // ---- 5. GEMM2: Hid[64x128] x W2 -> acc
#pragma unroll
        for (int mt = 0; mt < 4; ++mt) { acc[mt][0] = (f32x4)0.f; acc[mt][1] = (f32x4)0.f; }

#pragma unroll
        for (int kt = 0; kt < 4; ++kt) {
#pragma unroll
            for (int mt = 0; mt < 4; ++mt) {
                const s16x8 a = *(const s16x8*)&Hid[(mt * 16 + l15) * HS + kt * 32 + l4 * 8];
                acc[mt][0] = __builtin_amdgcn_mfma_f32_16x16x32_bf16(a, w2f[0][kt], acc[mt][0], 0, 0, 0);
                acc[mt][1] = __builtin_amdgcn_mfma_f32_16x16x32_bf16(a, w2f[1][kt], acc[mt][1], 0, 0, 0);
            }
        }

        // ---- 6. m = relu(acc+b2) -> Mbf
#pragma unroll
        for (int mt = 0; mt < 4; ++mt)
#pragma unroll
            for (int r = 0; r < 4; ++r) {
                const int row = mt * 16 + l4 * 4 + r;
                Mbf[row * HS + colbase + l15]      = f2bf(fmaxf(acc[mt][0][r] + b2c0, 0.f));
                Mbf[row * HS + colbase + 16 + l15] = f2bf(fmaxf(acc[mt][1][r] + b2c1, 0.f));
            }
        __syncthreads();             // barrier B: Mbf ready, A staged for next

        // ---- 7. full-tile segment reduce -> complete sums -> plain bf16 store
        if (tid < 128) {
            const int* idxp = idxbuf[p];
            const int c = tid;
            int cur = idxp[0];
            float s = 0.f;
            for (int r = 0; r < EMB; ++r) {
                const int d = idxp[r];            // wave-uniform
                if (d != cur) {
                    if (cur != 127)
                        agg16[(size_t)(ts + cur) * H + c] = f2bf(s);
                    s = 0.f; cur = d;
                }
                s += bf2f(Mbf[r * HS + c]);
            }
            if (cur != 127)
                agg16[(size_t)(ts + cur) * H + c] = f2bf(s);
        }

        ts = ts1; es = es1; ee = ee1;
        // reduce(k) reads idxbuf[p]/Mbf; next writers of those are gated by
        // barrier A of iteration k+1 -> safe without extra barrier here.
    }
}

// ---------------------------------------------------------------------------
// node update (MFMA, 64 rows/block): out = relu([h,agg]Wu+b);
// hbf = bf16(LN(out+h)). agg is bf16; residual read from staged LDS.
// ---------------------------------------------------------------------------
__global__ __launch_bounds__(256, 3)
void update_mfma(unsigned short* __restrict__ hbf,
                 const unsigned short* __restrict__ agg16,
                 const unsigned short* __restrict__ Wut, const float* __restrict__ b,
                 const float* __restrict__ g, const float* __restrict__ bln)
{
    __shared__ __align__(16) unsigned short A[UMB][US];  // 33792 B

    const int tid = threadIdx.x;
    const int n0 = blockIdx.x * UMB;
    const int wave = tid >> 6, lane = tid & 63, l15 = lane & 15, l4 = lane >> 4;
    const int colbase = wave * 32;

    // B fragments to registers
    s16x8 bf0[8], bf1[8];
#pragma unroll
    for (int kt = 0; kt < 8; ++kt) {
        bf0[kt] = *(const s16x8*)&Wut[(size_t)(colbase + l15) * 256 + kt * 32 + l4 * 8];
        bf1[kt] = *(const s16x8*)&Wut[(size_t)(colbase + 16 + l15) * 256 + kt * 32 + l4 * 8];
    }

    // stage h and agg (both bf16, direct uint4)
#pragma unroll
    for (int i = 0; i < 4; ++i) {
        const int f = tid + i * 256;
        const int row = f >> 4, c = f & 15;
        const int node = min(n0 + row, N_NODES - 1);
        const uint4 vh = *((const uint4*)(hbf + (size_t)node * H) + c);
        *(uint4*)&A[row][c * 8] = vh;
        const uint4 va = *((const uint4*)(agg16 + (size_t)node * H) + c);
        *(uint4*)&A[row][128 + c * 8] = va;
    }
    __syncthreads();

    f32x4 acc[4][2];
#pragma unroll
    for (int mt = 0; mt < 4; ++mt) { acc[mt][0] = (f32x4)0.f; acc[mt][1] = (f32x4)0.f; }

#pragma unroll
    for (int kt = 0; kt < 8; ++kt) {
#pragma unroll
        for (int mt = 0; mt < 4; ++mt) {
            const s16x8 a = *(const s16x8*)&A[mt * 16 + l15][kt * 32 + l4 * 8];
            acc[mt][0] = __builtin_amdgcn_mfma_f32_16x16x32_bf16(a, bf0[kt], acc[mt][0], 0, 0, 0);
            acc[mt][1] = __builtin_amdgcn_mfma_f32_16x16x32_bf16(a, bf1[kt], acc[mt][1], 0, 0, 0);
        }
    }
    __syncthreads();   // all A reads done before epilogue overlay

    // epilogue: relu(acc+b) -> bf16 into the agg half of A (cols 128..255)
    {
        const float bi0 = b[colbase + l15], bi1 = b[colbase + 16 + l15];
#pragma unroll
        for (int mt = 0; mt < 4; ++mt)
#pragma unroll
            for (int r = 0; r < 4; ++r) {
                const int row = mt * 16 + l4 * 4 + r;
                A[row][128 + colbase + l15]      = f2bf(fmaxf(acc[mt][0][r] + bi0, 0.f));
                A[row][128 + colbase + 16 + l15] = f2bf(fmaxf(acc[mt][1][r] + bi1, 0.f));
            }
    }
    __syncthreads();

    // LN: wave handles 16 rows; residual from staged h in A (cols 0..127)
    const float g0 = g[lane],   g1 = g[64 + lane];
    const float l0 = bln[lane], l1 = bln[64 + lane];
    for (int q = 0; q < 16; ++q) {
        const int row = wave * 16 + q;
        const int n = n0 + row;
        if (n >= N_NODES) break;
        float v0 = bf2f(A[row][128 + lane])      + bf2f(A[row][lane]);
        float v1 = bf2f(A[row][128 + 64 + lane]) + bf2f(A[row][64 + lane]);
        float s = v0 + v1;
#pragma unroll
        for (int off = 32; off > 0; off >>= 1) s += __shfl_xor(s, off, 64);
        const float mu = s * (1.f / 128.f);
        const float d0 = v0 - mu, d1 = v1 - mu;
        float vs = d0 * d0 + d1 * d1;
#pragma unroll
        for (int off = 32; off > 0; off >>= 1) vs += __shfl_xor(vs, off, 64);
        const float inv = rsqrtf(vs * (1.f / 128.f) + 1e-5f);
        hbf[(size_t)n * H + lane]      = f2bf(d0 * inv * g0 + l0);
        hbf[(size_t)n * H + 64 + lane] = f2bf(d1 * inv * g1 + l1);
    }
}

// ---------------------------------------------------------------------------
// final: out[c] = mean_n LN(hbf[n]; g,b)[c]
// ---------------------------------------------------------------------------
__global__ __launch_bounds__(256)
void final_kernel(const unsigned short* __restrict__ hbf,
                  const float* __restrict__ g, const float* __restrict__ b,
                  float* __restrict__ out)
{
    __shared__ float red[4][128];
    const int tid = threadIdx.x;
    const int wave = tid >> 6, lane = tid & 63;
    const float g0 = g[lane], g1 = g[64 + lane];
    const float b0 = b[lane], b1 = b[64 + lane];
    float a0 = 0.f, a1 = 0.f;

    for (int n = blockIdx.x * 4 + wave; n < N_NODES; n += gridDim.x * 4) {
        const float v0 = bf2f(hbf[(size_t)n * H + lane]);
        const float v1 = bf2f(hbf[(size_t)n * H + 64 + lane]);
        float s = v0 + v1;
#pragma unroll
        for (int off = 32; off > 0; off >>= 1) s += __shfl_xor(s, off, 64);
        const float mu = s * (1.f / 128.f);
        const float d0 = v0 - mu, d1 = v1 - mu;
        float vs = d0 * d0 + d1 * d1;
#pragma unroll
        for (int off = 32; off > 0; off >>= 1) vs += __shfl_xor(vs, off, 64);
        const float inv = rsqrtf(vs * (1.f / 128.f) + 1e-5f);
        a0 += d0 * inv * g0 + b0;
        a1 += d1 * inv * g1 + b1;
    }
    red[wave][lane]      = a0;
    red[wave][64 + lane] = a1;
    __syncthreads();
    if (wave == 0) {
        const float s0 = red[0][lane] + red[1][lane] + red[2][lane] + red[3][lane];
        const float s1 = red[0][64 + lane] + red[1][64 + lane] + red[2][64 + lane] + red[3][64 + lane];
        atomicAdd(&out[lane],      s0 * (1.f / N_NODES));
        atomicAdd(&out[64 + lane], s1 * (1.f / N_NODES));
    }
}

// ---------------------------------------------------------------------------
extern "C" void kernel_launch(void* const* d_in, const int* in_sizes, int n_in,
                              void* d_out, int out_size, void* d_ws, size_t ws_size,
                              hipStream_t stream)
{
    const float* x         = (const float*)d_in[0];
    const float* edge_attr = (const float*)d_in[1];
    const int*   edge_idx  = (const int*)  d_in[2];
    const float* proj_W    = (const float*)d_in[3];
    const float* proj_b    = (const float*)d_in[4];
    const float* msg_W1    = (const float*)d_in[5];
    const float* msg_b1    = (const float*)d_in[6];
    const float* msg_W2    = (const float*)d_in[7];
    const float* msg_b2    = (const float*)d_in[8];
    const float* upd_W     = (const float*)d_in[9];
    const float* upd_b     = (const float*)d_in[10];
    const float* ln_g      = (const float*)d_in[11];
    const float* ln_b      = (const float*)d_in[12];
    const float* out_g     = (const float*)d_in[13];
    const float* out_b     = (const float*)d_in[14];
    float* out = (float*)d_out;

    char* w = (char*)d_ws;
    unsigned short* agg16 = (unsigned short*)w; w += (size_t)N_NODES * H * 2;
    unsigned short* hbf   = (unsigned short*)w; w += (size_t)N_NODES * H * 2;
    unsigned short* eabf  = (unsigned short*)w; w += (size_t)N_EDGES * E_DIM * 2;
    unsigned short* W1t   = (unsigned short*)w; w += (size_t)NLAYERS * H * K1P * 2;
    unsigned short* W2t   = (unsigned short*)w; w += (size_t)NLAYERS * H * H * 2;
    unsigned short* Wut   = (unsigned short*)w; w += (size_t)NLAYERS * H * 256 * 2;
    unsigned short* Wpt   = (unsigned short*)w; w += (size_t)H * DIM_IN * 2;
    int* hist       = (int*)w;                  w += (size_t)N_NODES * 4;
    int* cursor     = (int*)w;                  w += (size_t)N_NODES * 4;
    int* node_start = (int*)w;                  w += (size_t)(N_NODES + 1) * 4;
    int* t_ns       = (int*)w;                  w += (size_t)(NTILES + 1) * 4;
    int* t_es       = (int*)w;                  w += (size_t)(NTILES + 1) * 4;
    int* i_s        = (int*)w;                  w += (size_t)N_EDGES * 4;
    int* j_s        = (int*)w;                  w += (size_t)N_EDGES * 4;
    int* perm       = (int*)w;                  w += (size_t)N_EDGES * 4;

    convert_w1<<<(NLAYERS * H * K1P) / 256, 256, 0, stream>>>(msg_W1, W1t);
    convert_w2<<<(NLAYERS * H * H) / 256, 256, 0, stream>>>(msg_W2, W2t);
    convert_wu<<<(NLAYERS * H * 256) / 256, 256, 0, stream>>>(upd_W, Wut);
    convert_wp<<<(H * DIM_IN) / 256, 256, 0, stream>>>(proj_W, Wpt);

    hipMemsetAsync(hist, 0, (size_t)N_NODES * 4, stream);
    hipMemsetAsync(agg16, 0, (size_t)N_NODES * H * 2, stream);   // degree-0 rows stay 0
    hist_kernel<<<(N_EDGES + 255) / 256, 256, 0, stream>>>(edge_idx, hist);
    scan_kernel<<<1, 256, 0, stream>>>(hist, cursor, node_start);
    scatter_kernel<<<(N_EDGES + 255) / 256, 256, 0, stream>>>(edge_idx, cursor, i_s, j_s, perm);
    convert_ea<<<(N_EDGES * 8) / 256, 256, 0, stream>>>(edge_attr, perm, eabf);
    tile_bounds<<<(NTILES + 1 + 255) / 256, 256, 0, stream>>>(node_start, t_ns, t_es);

    proj_mfma<<<(N_NODES + MB - 1) / MB, 256, 0, stream>>>(x, Wpt, proj_b, hbf);

    const int ublk = (N_NODES + UMB - 1) / UMB;
    for (int l = 0; l < NLAYERS; ++l) {
        edge_kernel<<<512, 256, 0, stream>>>(
            hbf, eabf, i_s, j_s, t_ns, t_es,
            W1t + (size_t)l * H * K1P, msg_b1 + (size_t)l * H,
            W2t + (size_t)l * H * H,   msg_b2 + (size_t)l * H, agg16);
        update_mfma<<<ublk, 256, 0, stream>>>(
            hbf, agg16, Wut + (size_t)l * H * 256, upd_b + (size_t)l * H,
            ln_g + (size_t)l * H, ln_b + (size_t)l * H);
    }

    hipMemsetAsync(out, 0, H * sizeof(float), stream);
    final_kernel<<<256, 256, 0, stream>>>(hbf, out_g, out_b, out);
}

// Round 10
// 894.201 us; speedup vs baseline: 1.3243x; 1.3243x over previous
//
#include <hip/hip_runtime.h>
#include <math.h>

#define N_NODES 50000
#define N_EDGES 400000
#define DIM_IN  128
#define H       128
#define E_DIM   16
#define NLAYERS 3

#define K1      272        // 2H + E_DIM
#define K1P     288        // padded to multiple of 32
#define AS      296        // edge A-tile row stride (shorts)
#define HS      136        // hid/m tile row stride (shorts)
#define US      264        // update A-tile row stride (shorts)
#define PS      136        // proj A-tile row stride (shorts)
#define FPS     132        // fp32 LDS row stride (floats), update epilogue
#define MB      32         // rows per proj/edge tile
#define UMB     64         // rows per update block
#define NT_E    (N_EDGES / MB)   // 12500 edge tiles

typedef short  s16x8 __attribute__((ext_vector_type(8)));
typedef float  f32x4 __attribute__((ext_vector_type(4)));

__device__ inline unsigned short f2bf(float f) {
    union { float f; unsigned u; } v; v.f = f;
    unsigned r = v.u + 0x7FFFu + ((v.u >> 16) & 1u);
    return (unsigned short)(r >> 16);
}
__device__ inline float bf2f(unsigned short u) {
    union { unsigned u; float f; } v; v.u = (unsigned)u << 16; return v.f;
}

// ---------------------------------------------------------------------------
// weight convert/transpose kernels (tiny, once per launch)
// ---------------------------------------------------------------------------
__global__ __launch_bounds__(256)
void convert_w1(const float* __restrict__ W1, unsigned short* __restrict__ W1t)
{   // [L][272][128] f32 -> [L][128][288] bf16 (zero pad)
    const int o = blockIdx.x * 256 + threadIdx.x;
    const int l = o / (128 * K1P);
    const int r = o % (128 * K1P);
    const int n = r / K1P;
    const int k = r % K1P;
    const float v = (k < K1) ? W1[(size_t)l * K1 * H + (size_t)k * H + n] : 0.f;
    W1t[o] = f2bf(v);
}

__global__ __launch_bounds__(256)
void convert_w2(const float* __restrict__ W2, unsigned short* __restrict__ W2t)
{   // [L][128][128] -> transposed bf16
    const int o = blockIdx.x * 256 + threadIdx.x;
    const int l = o / (H * H);
    const int r = o % (H * H);
    const int n = r / H;
    const int k = r % H;
    W2t[o] = f2bf(W2[(size_t)l * H * H + (size_t)k * H + n]);
}

__global__ __launch_bounds__(256)
void convert_wu(const float* __restrict__ Wu, unsigned short* __restrict__ Wut)
{   // [L][256][128] -> [L][128][256] bf16
    const int o = blockIdx.x * 256 + threadIdx.x;
    const int l = o / (H * 256);
    const int r = o % (H * 256);
    const int n = r / 256;
    const int k = r % 256;
    Wut[o] = f2bf(Wu[(size_t)l * 256 * H + (size_t)k * H + n]);
}

__global__ __launch_bounds__(256)
void convert_wp(const float* __restrict__ Wp, unsigned short* __restrict__ Wpt)
{   // [128][128] -> transposed bf16
    const int o = blockIdx.x * 256 + threadIdx.x;
    const int n = o / H;
    const int k = o % H;
    Wpt[o] = f2bf(Wp[(size_t)k * H + n]);
}

// edge_attr -> bf16 in sorted order
__global__ __launch_bounds__(256)
void convert_ea(const float* __restrict__ ea, const int* __restrict__ perm,
                unsigned short* __restrict__ eabf)
{
    const int o = blockIdx.x * 256 + threadIdx.x;
    const int p = o >> 3;
    const int j = (o & 7) * 2;
    const int pe = perm[p];
    const float2 v = *(const float2*)&ea[(size_t)pe * E_DIM + j];
    eabf[(size_t)p * E_DIM + j]     = f2bf(v.x);
    eabf[(size_t)p * E_DIM + j + 1] = f2bf(v.y);
}

// ---------------------------------------------------------------------------
// counting sort of edges by destination (i_idx)
// ---------------------------------------------------------------------------
__global__ __launch_bounds__(256)
void hist_kernel(const int* __restrict__ ei, int* __restrict__ hist)
{
    const int e = blockIdx.x * 256 + threadIdx.x;
    if (e < N_EDGES) atomicAdd(&hist[ei[e]], 1);
}

__global__ __launch_bounds__(256)
void scan_kernel(const int* __restrict__ hist, int* __restrict__ cursor)
{
    __shared__ int ps[256];
    const int t = threadIdx.x;
    const int CH = 196;
    const int base = t * CH;
    int s = 0;
    for (int i = 0; i < CH; ++i) { const int idx = base + i; if (idx < N_NODES) s += hist[idx]; }
    ps[t] = s; __syncthreads();
    for (int off = 1; off < 256; off <<= 1) {
        const int v = (t >= off) ? ps[t - off] : 0;
        __syncthreads();
        ps[t] += v;
        __syncthreads();
    }
    int run = (t > 0) ? ps[t - 1] : 0;
    for (int i = 0; i < CH; ++i) {
        const int idx = base + i;
        if (idx < N_NODES) { cursor[idx] = run; run += hist[idx]; }
    }
}

__global__ __launch_bounds__(256)
void scatter_kernel(const int* __restrict__ ei, int* __restrict__ cursor,
                    int* __restrict__ i_s, int* __restrict__ j_s, int* __restrict__ perm)
{
    const int e = blockIdx.x * 256 + threadIdx.x;
    if (e < N_EDGES) {
        const int d = ei[e];
        const int p = atomicAdd(&cursor[d], 1);
        i_s[p] = d;
        j_s[p] = ei[N_EDGES + e];
        perm[p] = e;
    }
}

// ---------------------------------------------------------------------------
// proj (MFMA): hbf = bf16(x @ Wp + b)
// ---------------------------------------------------------------------------
__global__ __launch_bounds__(256)
void proj_mfma(const float* __restrict__ x, const unsigned short* __restrict__ Wpt,
               const float* __restrict__ b, unsigned short* __restrict__ hbf)
{
    __shared__ __align__(16) unsigned short A[MB][PS];
    const int tid = threadIdx.x;
    const int n0 = blockIdx.x * MB;
    const int wave = tid >> 6, lane = tid & 63, l15 = lane & 15, l4 = lane >> 4;
    const int colbase = wave * 32;

#pragma unroll
    for (int i = 0; i < 4; ++i) {
        const int f = tid + i * 256;
        const int row = f >> 5, c4 = f & 31;
        const int node = min(n0 + row, N_NODES - 1);
        const float4 v = *((const float4*)(x + (size_t)node * DIM_IN) + c4);
        unsigned short o[4] = { f2bf(v.x), f2bf(v.y), f2bf(v.z), f2bf(v.w) };
        *(uint2*)&A[row][c4 * 4] = *(const uint2*)o;
    }
    __syncthreads();

    f32x4 acc[2][2];
#pragma unroll
    for (int mt = 0; mt < 2; ++mt)
#pragma unroll
        for (int nt = 0; nt < 2; ++nt) acc[mt][nt] = (f32x4)0.f;

    for (int k = 0; k < DIM_IN; k += 32) {
        const s16x8 a0 = *(const s16x8*)&A[l15][k + l4 * 8];
        const s16x8 a1 = *(const s16x8*)&A[16 + l15][k + l4 * 8];
        const s16x8 b0 = *(const s16x8*)&Wpt[(size_t)(colbase + l15) * DIM_IN + k + l4 * 8];
        const s16x8 b1 = *(const s16x8*)&Wpt[(size_t)(colbase + 16 + l15) * DIM_IN + k + l4 * 8];
        acc[0][0] = __builtin_amdgcn_mfma_f32_16x16x32_bf16(a0, b0, acc[0][0], 0, 0, 0);
        acc[0][1] = __builtin_amdgcn_mfma_f32_16x16x32_bf16(a0, b1, acc[0][1], 0, 0, 0);
        acc[1][0] = __builtin_amdgcn_mfma_f32_16x16x32_bf16(a1, b0, acc[1][0], 0, 0, 0);
        acc[1][1] = __builtin_amdgcn_mfma_f32_16x16x32_bf16(a1, b1, acc[1][1], 0, 0, 0);
    }

    const float bi0 = b[colbase + l15], bi1 = b[colbase + 16 + l15];
#pragma unroll
    for (int mt = 0; mt < 2; ++mt)
#pragma unroll
        for (int r = 0; r < 4; ++r) {
            const int row = mt * 16 + l4 * 4 + r;
            const int n = n0 + row;
            if (n < N_NODES) {
                hbf[(size_t)n * H + colbase + l15]      = f2bf(acc[mt][0][r] + bi0);
                hbf[(size_t)n * H + colbase + 16 + l15] = f2bf(acc[mt][1][r] + bi1);
            }
        }
}

// ---------------------------------------------------------------------------
// edge message MLP: 32-edge full-fill tiles, persistent blocks, 2 barriers,
// register prefetch + register weights, bf16 m-tile (36.6 KB LDS -> 4 blk/CU),
// hybrid reduce: interior segments = plain fp32 store (node fully inside tile),
// boundary segments (touch row 0/31) = atomicAdd.
// ---------------------------------------------------------------------------
__global__ __launch_bounds__(256, 4)
void edge_kernel(const unsigned short* __restrict__ hbf,
                 const unsigned short* __restrict__ eabf,  // [E][16] bf16, sorted
                 const int*   __restrict__ i_s,
                 const int*   __restrict__ j_s,
                 const unsigned short* __restrict__ W1t,   // [128][288]
                 const float* __restrict__ b1,
                 const unsigned short* __restrict__ W2t,   // [128][128]
                 const float* __restrict__ b2,
                 float*       __restrict__ agg)
{
    __shared__ __align__(16) unsigned short A[MB][AS];      // 18944 B
    __shared__ __align__(16) unsigned short Hid[MB * HS];   //  8704 B
    __shared__ __align__(16) unsigned short Mbf[MB * HS];   //  8704 B
    __shared__ int idxbuf[2][MB];                           //   256 B

    const int tid  = threadIdx.x;
    const int wave = tid >> 6;
    const int lane = tid & 63;
    const int l15  = lane & 15;
    const int l4   = lane >> 4;
    const int colbase = wave * 32;

    // gather role: thread covers (row = tid>>5 + 8i, c = tid&31), i=0..3
    const int ge_e = tid >> 5;
    const int ge_c = tid & 31;
    const int ge_ch = ge_c & 15;
    const int* __restrict__ gsel = (ge_c < 16) ? i_s : j_s;
    const int lds_off = (ge_c < 16 ? 0 : 128) + ge_ch * 8;

    // weights in registers (per wave: its 32 output cols)
    s16x8 w1f[2][9], w2f[2][4];
#pragma unroll
    for (int kt = 0; kt < 9; ++kt) {
        w1f[0][kt] = *(const s16x8*)&W1t[(size_t)(colbase + l15) * K1P + kt * 32 + l4 * 8];
        w1f[1][kt] = *(const s16x8*)&W1t[(size_t)(colbase + 16 + l15) * K1P + kt * 32 + l4 * 8];
    }
#pragma unroll
    for (int kt = 0; kt < 4; ++kt) {
        w2f[0][kt] = *(const s16x8*)&W2t[(size_t)(colbase + l15) * H + kt * 32 + l4 * 8];
        w2f[1][kt] = *(const s16x8*)&W2t[(size_t)(colbase + 16 + l15) * H + kt * 32 + l4 * 8];
    }
    const float b1c0 = b1[colbase + l15], b1c1 = b1[colbase + 16 + l15];
    const float b2c0 = b2[colbase + l15], b2c1 = b2[colbase + 16 + l15];

    int t = blockIdx.x;
    if (t >= NT_E) return;

    // ---- prologue: stage tile t into A / idxbuf[0]
    {
#pragma unroll
        for (int i = 0; i < 4; ++i) {
            const int node = gsel[t * MB + ge_e + i * 8];
            const uint4 v = *((const uint4*)(hbf + (size_t)node * H) + ge_ch);
            *(uint4*)&A[ge_e + i * 8][lds_off] = v;
        }
        if (tid < 64) {
            const uint4 va = *((const uint4*)eabf + (size_t)t * 64 + tid);
            *(uint4*)&A[tid >> 1][256 + (tid & 1) * 8] = va;
        } else if (tid < 128) {
            const int tt = tid - 64;
            const uint4 z = {0, 0, 0, 0};
            *(uint4*)&A[tt >> 1][272 + (tt & 1) * 8] = z;   // pad stays zero
        }
        if (tid < MB) idxbuf[0][tid] = i_s[t * MB + tid];
    }
    __syncthreads();

    int p = 0;
    for (; t < NT_E; t += gridDim.x, p ^= 1) {
        const int t1 = t + gridDim.x;

        // ---- 1. prefetch next tile into registers
        uint4 pf[4];
        uint4 pfa = {0, 0, 0, 0};
        int   pfi = 0;
        if (t1 < NT_E) {
#pragma unroll
            for (int i = 0; i < 4; ++i) {
                const int node = gsel[t1 * MB + ge_e + i * 8];
                pf[i] = *((const uint4*)(hbf + (size_t)node * H) + ge_ch);
            }
            if (tid < 64) pfa = *((const uint4*)eabf + (size_t)t1 * 64 + tid);
            if (tid < MB) pfi = i_s[t1 * MB + tid];
        }

        // ---- 2. GEMM1: A[32x288] x W1 -> acc
        f32x4 acc[2][2];
#pragma unroll
        for (int mt = 0; mt < 2; ++mt)
#pragma unroll
            for (int nt = 0; nt < 2; ++nt) acc[mt][nt] = (f32x4)0.f;

#pragma unroll
        for (int kt = 0; kt < 9; ++kt) {
            const s16x8 a0 = *(const s16x8*)&A[l15][kt * 32 + l4 * 8];
            const s16x8 a1 = *(const s16x8*)&A[16 + l15][kt * 32 + l4 * 8];
            acc[0][0] = __builtin_amdgcn_mfma_f32_16x16x32_bf16(a0, w1f[0][kt], acc[0][0], 0, 0, 0);
            acc[0][1] = __builtin_amdgcn_mfma_f32_16x16x32_bf16(a0, w1f[1][kt], acc[0][1], 0, 0, 0);
            acc[1][0] = __builtin_amdgcn_mfma_f32_16x16x32_bf16(a1, w1f[0][kt], acc[1][0], 0, 0, 0);
            acc[1][1] = __builtin_amdgcn_mfma_f32_16x16x32_bf16(a1, w1f[1][kt], acc[1][1], 0, 0, 0);
        }

        // ---- 3. hid = relu(acc+b1) -> Hid
#pragma unroll
        for (int mt = 0; mt < 2; ++mt)
#pragma unroll
            for (int r = 0; r < 4; ++r) {
                const int row = mt * 16 + l4 * 4 + r;
                Hid[row * HS + colbase + l15]      = f2bf(fmaxf(acc[mt][0][r] + b1c0, 0.f));
                Hid[row * HS + colbase + 16 + l15] = f2bf(fmaxf(acc[mt][1][r] + b1c1, 0.f));
            }
        __syncthreads();             // barrier A: A reads done, Hid ready

        // ---- 4. drain prefetch into A / idxbuf[p^1] (A free now)
        if (t1 < NT_E) {
#pragma unroll
            for (int i = 0; i < 4; ++i)
                *(uint4*)&A[ge_e + i * 8][lds_off] = pf[i];
            if (tid < 64)
                *(uint4*)&A[tid >> 1][256 + (tid & 1) * 8] = pfa;
            if (tid < MB) idxbuf[p ^ 1][tid] = pfi;
        }

        // ---- 5. GEMM2: Hid[32x128] x W2 -> acc
#pragma unroll
        for (int mt = 0; mt < 2; ++mt)
#pragma unroll
            for (int nt = 0; nt < 2; ++nt) acc[mt][nt] = (f32x4)0.f;

#pragma unroll
        for (int kt = 0; kt < 4; ++kt) {
            const s16x8 a0 = *(const s16x8*)&Hid[l15 * HS + kt * 32 + l4 * 8];
            const s16x8 a1 = *(const s16x8*)&Hid[(16 + l15) * HS + kt * 32 + l4 * 8];
            acc[0][0] = __builtin_amdgcn_mfma_f32_16x16x32_bf16(a0, w2f[0][kt], acc[0][0], 0, 0, 0);
            acc[0][1] = __builtin_amdgcn_mfma_f32_16x16x32_bf16(a0, w2f[1][kt], acc[0][1], 0, 0, 0);
            acc[1][0] = __builtin_amdgcn_mfma_f32_16x16x32_bf16(a1, w2f[0][kt], acc[1][0], 0, 0, 0);
            acc[1][1] = __builtin_amdgcn_mfma_f32_16x16x32_bf16(a1, w2f[1][kt], acc[1][1], 0, 0, 0);
        }

        // ---- 6. m = relu(acc+b2) -> Mbf (bf16, own region)
#pragma unroll
        for (int mt = 0; mt < 2; ++mt)
#pragma unroll
            for (int r = 0; r < 4; ++r) {
                const int row = mt * 16 + l4 * 4 + r;
                Mbf[row * HS + colbase + l15]      = f2bf(fmaxf(acc[mt][0][r] + b2c0, 0.f));
                Mbf[row * HS + colbase + 16 + l15] = f2bf(fmaxf(acc[mt][1][r] + b2c1, 0.f));
            }
        __syncthreads();             // barrier B: Mbf ready, A staged for next

        // ---- 7. hybrid full-window segment reduce:
        //         interior segment (no touch of row 0/31) => node's edges all
        //         in this tile => complete sum => plain store (exclusive).
        //         first/last segment => atomicAdd.
        if (tid < 128) {
            const int* idxp = idxbuf[p];
            const int c = tid;
            int cur = idxp[0];
            bool bnd = true;                 // first segment touches row 0
            float s = 0.f;
            for (int r = 0; r < MB; ++r) {
                const int d = idxp[r];       // wave-uniform
                if (d != cur) {
                    float* dst = &agg[(size_t)cur * H + c];
                    if (bnd) atomicAdd(dst, s); else *dst = s;
                    bnd = false;
                    s = 0.f; cur = d;
                }
                s += bf2f(Mbf[r * HS + c]);
            }
            atomicAdd(&agg[(size_t)cur * H + c], s);   // last touches row 31
        }
        // Mbf/idxbuf[p] readers finish before they reach barrier A of next
        // iteration, which gates the next writers -> safe with 2 barriers.
    }
}

// ---------------------------------------------------------------------------
// node update (MFMA, 64 rows/block): out = relu([h,agg]Wu+b);
// hbf = bf16(LN(out+h)); agg rows re-zeroed for next layer (replaces memset).
// ---------------------------------------------------------------------------
__global__ __launch_bounds__(256, 3)
void update_mfma(unsigned short* __restrict__ hbf, float* __restrict__ agg,
                 const unsigned short* __restrict__ Wut, const float* __restrict__ b,
                 const float* __restrict__ g, const float* __restrict__ bln)
{
    __shared__ __align__(16) unsigned short A[UMB][US];  // 33792 B
    float* Afp = (float*)&A[0][0];                       // [64][FPS] overlay

    const int tid = threadIdx.x;
    const int n0 = blockIdx.x * UMB;
    const int wave = tid >> 6, lane = tid & 63, l15 = lane & 15, l4 = lane >> 4;
    const int colbase = wave * 32;

    // B fragments to registers
    s16x8 bf0[8], bf1[8];
#pragma unroll
    for (int kt = 0; kt < 8; ++kt) {
        bf0[kt] = *(const s16x8*)&Wut[(size_t)(colbase + l15) * 256 + kt * 32 + l4 * 8];
        bf1[kt] = *(const s16x8*)&Wut[(size_t)(colbase + 16 + l15) * 256 + kt * 32 + l4 * 8];
    }

    // stage h (bf16 direct)
#pragma unroll
    for (int i = 0; i < 4; ++i) {
        const int f = tid + i * 256;
        const int row = f >> 4, c = f & 15;
        const int node = min(n0 + row, N_NODES - 1);
        const uint4 v = *((const uint4*)(hbf + (size_t)node * H) + c);
        *(uint4*)&A[row][c * 8] = v;
    }
    // stage agg (fp32 -> bf16) and re-zero owned rows (replaces next memset)
#pragma unroll
    for (int i = 0; i < 8; ++i) {
        const int f = tid + i * 256;
        const int row = f >> 5, c4 = f & 31;
        const int node = min(n0 + row, N_NODES - 1);
        float4* ap = (float4*)(agg + (size_t)node * H) + c4;
        const float4 v = *ap;
        if (n0 + row < N_NODES) {
            const float4 z = {0.f, 0.f, 0.f, 0.f};
            *ap = z;
        }
        unsigned short o[4] = { f2bf(v.x), f2bf(v.y), f2bf(v.z), f2bf(v.w) };
        *(uint2*)&A[row][128 + c4 * 4] = *(const uint2*)o;
    }
    __syncthreads();

    f32x4 acc[4][2];
#pragma unroll
    for (int mt = 0; mt < 4; ++mt) { acc[mt][0] = (f32x4)0.f; acc[mt][1] = (f32x4)0.f; }

#pragma unroll
    for (int kt = 0; kt < 8; ++kt) {
#pragma unroll
        for (int mt = 0; mt < 4; ++mt) {
            const s16x8 a = *(const s16x8*)&A[mt * 16 + l15][kt * 32 + l4 * 8];
            acc[mt][0] = __builtin_amdgcn_mfma_f32_16x16x32_bf16(a, bf0[kt], acc[mt][0], 0, 0, 0);
            acc[mt][1] = __builtin_amdgcn_mfma_f32_16x16x32_bf16(a, bf1[kt], acc[mt][1], 0, 0, 0);
        }
    }
    __syncthreads();   // all A reads done before fp32 overlay

    {
        const float bi0 = b[colbase + l15], bi1 = b[colbase + 16 + l15];
#pragma unroll
        for (int mt = 0; mt < 4; ++mt)
#pragma unroll
            for (int r = 0; r < 4; ++r) {
                const int row = mt * 16 + l4 * 4 + r;
                Afp[row * FPS + colbase + l15]      = fmaxf(acc[mt][0][r] + bi0, 0.f);
                Afp[row * FPS + colbase + 16 + l15] = fmaxf(acc[mt][1][r] + bi1, 0.f);
            }
    }
    __syncthreads();

    // LN: wave handles 16 rows; residual re-read from L2-hot hbf
    const float g0 = g[lane],   g1 = g[64 + lane];
    const float l0 = bln[lane], l1 = bln[64 + lane];
    for (int q = 0; q < 16; ++q) {
        const int row = wave * 16 + q;
        const int n = n0 + row;
        if (n >= N_NODES) break;
        const float hr0 = bf2f(hbf[(size_t)n * H + lane]);
        const float hr1 = bf2f(hbf[(size_t)n * H + 64 + lane]);
        float v0 = Afp[row * FPS + lane]      + hr0;
        float v1 = Afp[row * FPS + 64 + lane] + hr1;
        float s = v0 + v1;
#pragma unroll
        for (int off = 32; off > 0; off >>= 1) s += __shfl_xor(s, off, 64);
        const float mu = s * (1.f / 128.f);
        const float d0 = v0 - mu, d1 = v1 - mu;
        float vs = d0 * d0 + d1 * d1;
#pragma unroll
        for (int off = 32; off > 0; off >>= 1) vs += __shfl_xor(vs, off, 64);
        const float inv = rsqrtf(vs * (1.f / 128.f) + 1e-5f);
        hbf[(size_t)n * H + lane]      = f2bf(d0 * inv * g0 + l0);
        hbf[(size_t)n * H + 64 + lane] = f2bf(d1 * inv * g1 + l1);
    }
}

// ---------------------------------------------------------------------------
// final: out[c] = mean_n LN(hbf[n]; g,b)[c]
// ---------------------------------------------------------------------------
__global__ __launch_bounds__(256)
void final_kernel(const unsigned short* __restrict__ hbf,
                  const float* __restrict__ g, const float* __restrict__ b,
                  float* __restrict__ out)
{
    __shared__ float red[4][128];
    const int tid = threadIdx.x;
    const int wave = tid >> 6, lane = tid & 63;
    const float g0 = g[lane], g1 = g[64 + lane];
    const float b0 = b[lane], b1 = b[64 + lane];
    float a0 = 0.f, a1 = 0.f;

    for (int n = blockIdx.x * 4 + wave; n < N_NODES; n += gridDim.x * 4) {
        const float v0 = bf2f(hbf[(size_t)n * H + lane]);
        const float v1 = bf2f(hbf[(size_t)n * H + 64 + lane]);
        float s = v0 + v1;
#pragma unroll
        for (int off = 32; off > 0; off >>= 1) s += __shfl_xor(s, off, 64);
        const float mu = s * (1.f / 128.f);
        const float d0 = v0 - mu, d1 = v1 - mu;
        float vs = d0 * d0 + d1 * d1;
#pragma unroll
        for (int off = 32; off > 0; off >>= 1) vs += __shfl_xor(vs, off, 64);
        const float inv = rsqrtf(vs * (1.f / 128.f) + 1e-5f);
        a0 += d0 * inv * g0 + b0;
        a1 += d1 * inv * g1 + b1;
    }
    red[wave][lane]      = a0;
    red[wave][64 + lane] = a1;
    __syncthreads();
    if (wave == 0) {
        const float s0 = red[0][lane] + red[1][lane] + red[2][lane] + red[3][lane];
        const float s1 = red[0][64 + lane] + red[1][64 + lane] + red[2][64 + lane] + red[3][64 + lane];
        atomicAdd(&out[lane],      s0 * (1.f / N_NODES));
        atomicAdd(&out[64 + lane], s1 * (1.f / N_NODES));
    }
}

// ---------------------------------------------------------------------------
extern "C" void kernel_launch(void* const* d_in, const int* in_sizes, int n_in,
                              void* d_out, int out_size, void* d_ws, size_t ws_size,
                              hipStream_t stream)
{
    const float* x         = (const float*)d_in[0];
    const float* edge_attr = (const float*)d_in[1];
    const int*   edge_idx  = (const int*)  d_in[2];
    const float* proj_W    = (const float*)d_in[3];
    const float* proj_b    = (const float*)d_in[4];
    const float* msg_W1    = (const float*)d_in[5];
    const float* msg_b1    = (const float*)d_in[6];
    const float* msg_W2    = (const float*)d_in[7];
    const float* msg_b2    = (const float*)d_in[8];
    const float* upd_W     = (const float*)d_in[9];
    const float* upd_b     = (const float*)d_in[10];
    const float* ln_g      = (const float*)d_in[11];
    const float* ln_b      = (const float*)d_in[12];
    const float* out_g     = (const float*)d_in[13];
    const float* out_b     = (const float*)d_in[14];
    float* out = (float*)d_out;

    char* w = (char*)d_ws;
    float* agg = (float*)w;                   w += (size_t)N_NODES * H * 4;
    unsigned short* hbf  = (unsigned short*)w; w += (size_t)N_NODES * H * 2;
    unsigned short* eabf = (unsigned short*)w; w += (size_t)N_EDGES * E_DIM * 2;
    unsigned short* W1t  = (unsigned short*)w; w += (size_t)NLAYERS * H * K1P * 2;
    unsigned short* W2t  = (unsigned short*)w; w += (size_t)NLAYERS * H * H * 2;
    unsigned short* Wut  = (unsigned short*)w; w += (size_t)NLAYERS * H * 256 * 2;
    unsigned short* Wpt  = (unsigned short*)w; w += (size_t)H * DIM_IN * 2;
    int* hist   = (int*)w;                    w += (size_t)N_NODES * 4;
    int* cursor = (int*)w;                    w += (size_t)N_NODES * 4;
    int* i_s    = (int*)w;                    w += (size_t)N_EDGES * 4;
    int* j_s    = (int*)w;                    w += (size_t)N_EDGES * 4;
    int* perm   = (int*)w;                    w += (size_t)N_EDGES * 4;

    convert_w1<<<(NLAYERS * H * K1P) / 256, 256, 0, stream>>>(msg_W1, W1t);
    convert_w2<<<(NLAYERS * H * H) / 256, 256, 0, stream>>>(msg_W2, W2t);
    convert_wu<<<(NLAYERS * H * 256) / 256, 256, 0, stream>>>(upd_W, Wut);
    convert_wp<<<(H * DIM_IN) / 256, 256, 0, stream>>>(proj_W, Wpt);

    hipMemsetAsync(hist, 0, (size_t)N_NODES * 4, stream);
    hipMemsetAsync(agg, 0, (size_t)N_NODES * H * sizeof(float), stream);  // once; update re-zeroes
    hist_kernel<<<(N_EDGES + 255) / 256, 256, 0, stream>>>(edge_idx, hist);
    scan_kernel<<<1, 256, 0, stream>>>(hist, cursor);
    scatter_kernel<<<(N_EDGES + 255) / 256, 256, 0, stream>>>(edge_idx, cursor, i_s, j_s, perm);
    convert_ea<<<(N_EDGES * 8) / 256, 256, 0, stream>>>(edge_attr, perm, eabf);

    proj_mfma<<<(N_NODES + MB - 1) / MB, 256, 0, stream>>>(x, Wpt, proj_b, hbf);

    const int ublk = (N_NODES + UMB - 1) / UMB;
    for (int l = 0; l < NLAYERS; ++l) {
        edge_kernel<<<1024, 256, 0, stream>>>(
            hbf, eabf, i_s, j_s,
            W1t + (size_t)l * H * K1P, msg_b1 + (size_t)l * H,
            W2t + (size_t)l * H * H,   msg_b2 + (size_t)l * H, agg);
        update_mfma<<<ublk, 256, 0, stream>>>(
            hbf, agg, Wut + (size_t)l * H * 256, upd_b + (size_t)l * H,
            ln_g + (size_t)l * H, ln_b + (size_t)l * H);
    }

    hipMemsetAsync(out, 0, H * sizeof(float), stream);
    final_kernel<<<256, 256, 0, stream>>>(hbf, out_g, out_b, out);
}

// Round 11
// 795.705 us; speedup vs baseline: 1.4882x; 1.1238x over previous
//
#include <hip/hip_runtime.h>
#include <math.h>

#define N_NODES 50000
#define N_EDGES 400000
#define DIM_IN  128
#define H       128
#define E_DIM   16
#define NLAYERS 3

#define K1      272        // 2H + E_DIM
#define K1P     288        // padded to multiple of 32
#define AS      296        // edge A-tile row stride (shorts)
#define HS      136        // hid/m tile row stride (shorts)
#define US      264        // update A-tile row stride (shorts)
#define PS      136        // proj A-tile row stride (shorts)
#define FPS     132        // fp32 LDS row stride (floats), update epilogue
#define MB      32         // rows per proj/edge tile
#define UMB     64         // rows per update block
#define NT_E    (N_EDGES / MB)   // 12500 edge tiles

typedef short  s16x8 __attribute__((ext_vector_type(8)));
typedef float  f32x4 __attribute__((ext_vector_type(4)));

__device__ inline unsigned short f2bf(float f) {
    union { float f; unsigned u; } v; v.f = f;
    unsigned r = v.u + 0x7FFFu + ((v.u >> 16) & 1u);
    return (unsigned short)(r >> 16);
}
__device__ inline float bf2f(unsigned short u) {
    union { unsigned u; float f; } v; v.u = (unsigned)u << 16; return v.f;
}

// ---------------------------------------------------------------------------
// weight convert/transpose kernels (tiny, once per launch)
// ---------------------------------------------------------------------------
__global__ __launch_bounds__(256)
void convert_w1(const float* __restrict__ W1, unsigned short* __restrict__ W1t)
{   // [L][272][128] f32 -> [L][128][288] bf16 (zero pad)
    const int o = blockIdx.x * 256 + threadIdx.x;
    const int l = o / (128 * K1P);
    const int r = o % (128 * K1P);
    const int n = r / K1P;
    const int k = r % K1P;
    const float v = (k < K1) ? W1[(size_t)l * K1 * H + (size_t)k * H + n] : 0.f;
    W1t[o] = f2bf(v);
}

__global__ __launch_bounds__(256)
void convert_w2(const float* __restrict__ W2, unsigned short* __restrict__ W2t)
{   // [L][128][128] -> transposed bf16
    const int o = blockIdx.x * 256 + threadIdx.x;
    const int l = o / (H * H);
    const int r = o % (H * H);
    const int n = r / H;
    const int k = r % H;
    W2t[o] = f2bf(W2[(size_t)l * H * H + (size_t)k * H + n]);
}

__global__ __launch_bounds__(256)
void convert_wu(const float* __restrict__ Wu, unsigned short* __restrict__ Wut)
{   // [L][256][128] -> [L][128][256] bf16
    const int o = blockIdx.x * 256 + threadIdx.x;
    const int l = o / (H * 256);
    const int r = o % (H * 256);
    const int n = r / 256;
    const int k = r % 256;
    Wut[o] = f2bf(Wu[(size_t)l * 256 * H + (size_t)k * H + n]);
}

__global__ __launch_bounds__(256)
void convert_wp(const float* __restrict__ Wp, unsigned short* __restrict__ Wpt)
{   // [128][128] -> transposed bf16
    const int o = blockIdx.x * 256 + threadIdx.x;
    const int n = o / H;
    const int k = o % H;
    Wpt[o] = f2bf(Wp[(size_t)k * H + n]);
}

// edge_attr -> bf16 in sorted order
__global__ __launch_bounds__(256)
void convert_ea(const float* __restrict__ ea, const int* __restrict__ perm,
                unsigned short* __restrict__ eabf)
{
    const int o = blockIdx.x * 256 + threadIdx.x;
    const int p = o >> 3;
    const int j = (o & 7) * 2;
    const int pe = perm[p];
    const float2 v = *(const float2*)&ea[(size_t)pe * E_DIM + j];
    eabf[(size_t)p * E_DIM + j]     = f2bf(v.x);
    eabf[(size_t)p * E_DIM + j + 1] = f2bf(v.y);
}

// ---------------------------------------------------------------------------
// counting sort of edges by destination (i_idx)
// ---------------------------------------------------------------------------
__global__ __launch_bounds__(256)
void hist_kernel(const int* __restrict__ ei, int* __restrict__ hist)
{
    const int e = blockIdx.x * 256 + threadIdx.x;
    if (e < N_EDGES) atomicAdd(&hist[ei[e]], 1);
}

__global__ __launch_bounds__(256)
void scan_kernel(const int* __restrict__ hist, int* __restrict__ cursor)
{
    __shared__ int ps[256];
    const int t = threadIdx.x;
    const int CH = 196;
    const int base = t * CH;
    int s = 0;
    for (int i = 0; i < CH; ++i) { const int idx = base + i; if (idx < N_NODES) s += hist[idx]; }
    ps[t] = s; __syncthreads();
    for (int off = 1; off < 256; off <<= 1) {
        const int v = (t >= off) ? ps[t - off] : 0;
        __syncthreads();
        ps[t] += v;
        __syncthreads();
    }
    int run = (t > 0) ? ps[t - 1] : 0;
    for (int i = 0; i < CH; ++i) {
        const int idx = base + i;
        if (idx < N_NODES) { cursor[idx] = run; run += hist[idx]; }
    }
}

__global__ __launch_bounds__(256)
void scatter_kernel(const int* __restrict__ ei, int* __restrict__ cursor,
                    int* __restrict__ i_s, int* __restrict__ j_s, int* __restrict__ perm)
{
    const int e = blockIdx.x * 256 + threadIdx.x;
    if (e < N_EDGES) {
        const int d = ei[e];
        const int p = atomicAdd(&cursor[d], 1);
        i_s[p] = d;
        j_s[p] = ei[N_EDGES + e];
        perm[p] = e;
    }
}

// ---------------------------------------------------------------------------
// proj (MFMA): hbf = bf16(x @ Wp + b)
// ---------------------------------------------------------------------------
__global__ __launch_bounds__(256)
void proj_mfma(const float* __restrict__ x, const unsigned short* __restrict__ Wpt,
               const float* __restrict__ b, unsigned short* __restrict__ hbf)
{
    __shared__ __align__(16) unsigned short A[MB][PS];
    const int tid = threadIdx.x;
    const int n0 = blockIdx.x * MB;
    const int wave = tid >> 6, lane = tid & 63, l15 = lane & 15, l4 = lane >> 4;
    const int colbase = wave * 32;

#pragma unroll
    for (int i = 0; i < 4; ++i) {
        const int f = tid + i * 256;
        const int row = f >> 5, c4 = f & 31;
        const int node = min(n0 + row, N_NODES - 1);
        const float4 v = *((const float4*)(x + (size_t)node * DIM_IN) + c4);
        unsigned short o[4] = { f2bf(v.x), f2bf(v.y), f2bf(v.z), f2bf(v.w) };
        *(uint2*)&A[row][c4 * 4] = *(const uint2*)o;
    }
    __syncthreads();

    f32x4 acc[2][2];
#pragma unroll
    for (int mt = 0; mt < 2; ++mt)
#pragma unroll
        for (int nt = 0; nt < 2; ++nt) acc[mt][nt] = (f32x4)0.f;

    for (int k = 0; k < DIM_IN; k += 32) {
        const s16x8 a0 = *(const s16x8*)&A[l15][k + l4 * 8];
        const s16x8 a1 = *(const s16x8*)&A[16 + l15][k + l4 * 8];
        const s16x8 b0 = *(const s16x8*)&Wpt[(size_t)(colbase + l15) * DIM_IN + k + l4 * 8];
        const s16x8 b1 = *(const s16x8*)&Wpt[(size_t)(colbase + 16 + l15) * DIM_IN + k + l4 * 8];
        acc[0][0] = __builtin_amdgcn_mfma_f32_16x16x32_bf16(a0, b0, acc[0][0], 0, 0, 0);
        acc[0][1] = __builtin_amdgcn_mfma_f32_16x16x32_bf16(a0, b1, acc[0][1], 0, 0, 0);
        acc[1][0] = __builtin_amdgcn_mfma_f32_16x16x32_bf16(a1, b0, acc[1][0], 0, 0, 0);
        acc[1][1] = __builtin_amdgcn_mfma_f32_16x16x32_bf16(a1, b1, acc[1][1], 0, 0, 0);
    }

    const float bi0 = b[colbase + l15], bi1 = b[colbase + 16 + l15];
#pragma unroll
    for (int mt = 0; mt < 2; ++mt)
#pragma unroll
        for (int r = 0; r < 4; ++r) {
            const int row = mt * 16 + l4 * 4 + r;
            const int n = n0 + row;
            if (n < N_NODES) {
                hbf[(size_t)n * H + colbase + l15]      = f2bf(acc[mt][0][r] + bi0);
                hbf[(size_t)n * H + colbase + 16 + l15] = f2bf(acc[mt][1][r] + bi1);
            }
        }
}

// ---------------------------------------------------------------------------
// edge message MLP: 32-edge full-fill tiles, persistent blocks, 2 barriers,
// register prefetch + register weights, bf16 m-tile (36.6 KB LDS),
// hybrid reduce: interior segments = plain fp32 store, boundary = atomicAdd.
// __launch_bounds__(256,3): VGPR cap ~168 -> NO spill (R10's (256,4)=64 cap
// spilled to scratch: FETCH 331 MB). 3 blocks/CU.
// ---------------------------------------------------------------------------
__global__ __launch_bounds__(256, 3)
void edge_kernel(const unsigned short* __restrict__ hbf,
                 const unsigned short* __restrict__ eabf,  // [E][16] bf16, sorted
                 const int*   __restrict__ i_s,
                 const int*   __restrict__ j_s,
                 const unsigned short* __restrict__ W1t,   // [128][288]
                 const float* __restrict__ b1,
                 const unsigned short* __restrict__ W2t,   // [128][128]
                 const float* __restrict__ b2,
                 float*       __restrict__ agg)
{
    __shared__ __align__(16) unsigned short A[MB][AS];      // 18944 B
    __shared__ __align__(16) unsigned short Hid[MB * HS];   //  8704 B
    __shared__ __align__(16) unsigned short Mbf[MB * HS];   //  8704 B
    __shared__ int idxbuf[2][MB];                           //   256 B

    const int tid  = threadIdx.x;
    const int wave = tid >> 6;
    const int lane = tid & 63;
    const int l15  = lane & 15;
    const int l4   = lane >> 4;
    const int colbase = wave * 32;

    // gather role: thread covers (row = tid>>5 + 8i, c = tid&31), i=0..3
    const int ge_e = tid >> 5;
    const int ge_c = tid & 31;
    const int ge_ch = ge_c & 15;
    const int* __restrict__ gsel = (ge_c < 16) ? i_s : j_s;
    const int lds_off = (ge_c < 16 ? 0 : 128) + ge_ch * 8;

    // weights in registers (per wave: its 32 output cols)
    s16x8 w1f[2][9], w2f[2][4];
#pragma unroll
    for (int kt = 0; kt < 9; ++kt) {
        w1f[0][kt] = *(const s16x8*)&W1t[(size_t)(colbase + l15) * K1P + kt * 32 + l4 * 8];
        w1f[1][kt] = *(const s16x8*)&W1t[(size_t)(colbase + 16 + l15) * K1P + kt * 32 + l4 * 8];
    }
#pragma unroll
    for (int kt = 0; kt < 4; ++kt) {
        w2f[0][kt] = *(const s16x8*)&W2t[(size_t)(colbase + l15) * H + kt * 32 + l4 * 8];
        w2f[1][kt] = *(const s16x8*)&W2t[(size_t)(colbase + 16 + l15) * H + kt * 32 + l4 * 8];
    }
    const float b1c0 = b1[colbase + l15], b1c1 = b1[colbase + 16 + l15];
    const float b2c0 = b2[colbase + l15], b2c1 = b2[colbase + 16 + l15];

    int t = blockIdx.x;
    if (t >= NT_E) return;

    // ---- prologue: stage tile t into A / idxbuf[0]
    {
#pragma unroll
        for (int i = 0; i < 4; ++i) {
            const int node = gsel[t * MB + ge_e + i * 8];
            const uint4 v = *((const uint4*)(hbf + (size_t)node * H) + ge_ch);
            *(uint4*)&A[ge_e + i * 8][lds_off] = v;
        }
        if (tid < 64) {
            const uint4 va = *((const uint4*)eabf + (size_t)t * 64 + tid);
            *(uint4*)&A[tid >> 1][256 + (tid & 1) * 8] = va;
        } else if (tid < 128) {
            const int tt = tid - 64;
            const uint4 z = {0, 0, 0, 0};
            *(uint4*)&A[tt >> 1][272 + (tt & 1) * 8] = z;   // pad stays zero
        }
        if (tid < MB) idxbuf[0][tid] = i_s[t * MB + tid];
    }
    __syncthreads();

    int p = 0;
    for (; t < NT_E; t += gridDim.x, p ^= 1) {
        const int t1 = t + gridDim.x;

        // ---- 1. prefetch next tile into registers
        uint4 pf[4];
        uint4 pfa = {0, 0, 0, 0};
        int   pfi = 0;
        if (t1 < NT_E) {
#pragma unroll
            for (int i = 0; i < 4; ++i) {
                const int node = gsel[t1 * MB + ge_e + i * 8];
                pf[i] = *((const uint4*)(hbf + (size_t)node * H) + ge_ch);
            }
            if (tid < 64) pfa = *((const uint4*)eabf + (size_t)t1 * 64 + tid);
            if (tid < MB) pfi = i_s[t1 * MB + tid];
        }

        // ---- 2. GEMM1: A[32x288] x W1 -> acc
        f32x4 acc[2][2];
#pragma unroll
        for (int mt = 0; mt < 2; ++mt)
#pragma unroll
            for (int nt = 0; nt < 2; ++nt) acc[mt][nt] = (f32x4)0.f;

#pragma unroll
        for (int kt = 0; kt < 9; ++kt) {
            const s16x8 a0 = *(const s16x8*)&A[l15][kt * 32 + l4 * 8];
            const s16x8 a1 = *(const s16x8*)&A[16 + l15][kt * 32 + l4 * 8];
            acc[0][0] = __builtin_amdgcn_mfma_f32_16x16x32_bf16(a0, w1f[0][kt], acc[0][0], 0, 0, 0);
            acc[0][1] = __builtin_amdgcn_mfma_f32_16x16x32_bf16(a0, w1f[1][kt], acc[0][1], 0, 0, 0);
            acc[1][0] = __builtin_amdgcn_mfma_f32_16x16x32_bf16(a1, w1f[0][kt], acc[1][0], 0, 0, 0);
            acc[1][1] = __builtin_amdgcn_mfma_f32_16x16x32_bf16(a1, w1f[1][kt], acc[1][1], 0, 0, 0);
        }

        // ---- 3. hid = relu(acc+b1) -> Hid
#pragma unroll
        for (int mt = 0; mt < 2; ++mt)
#pragma unroll
            for (int r = 0; r < 4; ++r) {
                const int row = mt * 16 + l4 * 4 + r;
                Hid[row * HS + colbase + l15]      = f2bf(fmaxf(acc[mt][0][r] + b1c0, 0.f));
                Hid[row * HS + colbase + 16 + l15] = f2bf(fmaxf(acc[mt][1][r] + b1c1, 0.f));
            }
        __syncthreads();             // barrier A: A reads done, Hid ready

        // ---- 4. drain prefetch into A / idxbuf[p^1] (A free now)
        if (t1 < NT_E) {
#pragma unroll
            for (int i = 0; i < 4; ++i)
                *(uint4*)&A[ge_e + i * 8][lds_off] = pf[i];
            if (tid < 64)
                *(uint4*)&A[tid >> 1][256 + (tid & 1) * 8] = pfa;
            if (tid < MB) idxbuf[p ^ 1][tid] = pfi;
        }

        // ---- 5. GEMM2: Hid[32x128] x W2 -> acc
#pragma unroll
        for (int mt = 0; mt < 2; ++mt)
#pragma unroll
            for (int nt = 0; nt < 2; ++nt) acc[mt][nt] = (f32x4)0.f;

#pragma unroll
        for (int kt = 0; kt < 4; ++kt) {
            const s16x8 a0 = *(const s16x8*)&Hid[l15 * HS + kt * 32 + l4 * 8];
            const s16x8 a1 = *(const s16x8*)&Hid[(16 + l15) * HS + kt * 32 + l4 * 8];
            acc[0][0] = __builtin_amdgcn_mfma_f32_16x16x32_bf16(a0, w2f[0][kt], acc[0][0], 0, 0, 0);
            acc[0][1] = __builtin_amdgcn_mfma_f32_16x16x32_bf16(a0, w2f[1][kt], acc[0][1], 0, 0, 0);
            acc[1][0] = __builtin_amdgcn_mfma_f32_16x16x32_bf16(a1, w2f[0][kt], acc[1][0], 0, 0, 0);
            acc[1][1] = __builtin_amdgcn_mfma_f32_16x16x32_bf16(a1, w2f[1][kt], acc[1][1], 0, 0, 0);
        }

        // ---- 6. m = relu(acc+b2) -> Mbf (bf16, own region)
#pragma unroll
        for (int mt = 0; mt < 2; ++mt)
#pragma unroll
            for (int r = 0; r < 4; ++r) {
                const int row = mt * 16 + l4 * 4 + r;
                Mbf[row * HS + colbase + l15]      = f2bf(fmaxf(acc[mt][0][r] + b2c0, 0.f));
                Mbf[row * HS + colbase + 16 + l15] = f2bf(fmaxf(acc[mt][1][r] + b2c1, 0.f));
            }
        __syncthreads();             // barrier B: Mbf ready, A staged for next

        // ---- 7. hybrid full-window segment reduce:
        //         interior segment => node's edges all in this tile => plain
        //         store; first/last segment (touch row 0/31) => atomicAdd.
        if (tid < 128) {
            const int* idxp = idxbuf[p];
            const int c = tid;
            int cur = idxp[0];
            bool bnd = true;                 // first segment touches row 0
            float s = 0.f;
            for (int r = 0; r < MB; ++r) {
                const int d = idxp[r];       // wave-uniform
                if (d != cur) {
                    float* dst = &agg[(size_t)cur * H + c];
                    if (bnd) atomicAdd(dst, s); else *dst = s;
                    bnd = false;
                    s = 0.f; cur = d;
                }
                s += bf2f(Mbf[r * HS + c]);
            }
            atomicAdd(&agg[(size_t)cur * H + c], s);   // last touches row 31
        }
        // Mbf/idxbuf[p] readers finish before barrier A of next iteration,
        // which gates the next writers -> safe with 2 barriers.
    }
}

// ---------------------------------------------------------------------------
// node update (MFMA, 64 rows/block): out = relu([h,agg]Wu+b);
// hbf = bf16(LN(out+h)); agg rows re-zeroed for next layer (replaces memset).
// ---------------------------------------------------------------------------
__global__ __launch_bounds__(256, 3)
void update_mfma(unsigned short* __restrict__ hbf, float* __restrict__ agg,
                 const unsigned short* __restrict__ Wut, const float* __restrict__ b,
                 const float* __restrict__ g, const float* __restrict__ bln)
{
    __shared__ __align__(16) unsigned short A[UMB][US];  // 33792 B
    float* Afp = (float*)&A[0][0];                       // [64][FPS] overlay

    const int tid = threadIdx.x;
    const int n0 = blockIdx.x * UMB;
    const int wave = tid >> 6, lane = tid & 63, l15 = lane & 15, l4 = lane >> 4;
    const int colbase = wave * 32;

    // B fragments to registers
    s16x8 bf0[8], bf1[8];
#pragma unroll
    for (int kt = 0; kt < 8; ++kt) {
        bf0[kt] = *(const s16x8*)&Wut[(size_t)(colbase + l15) * 256 + kt * 32 + l4 * 8];
        bf1[kt] = *(const s16x8*)&Wut[(size_t)(colbase + 16 + l15) * 256 + kt * 32 + l4 * 8];
    }

    // stage h (bf16 direct)
#pragma unroll
    for (int i = 0; i < 4; ++i) {
        const int f = tid + i * 256;
        const int row = f >> 4, c = f & 15;
        const int node = min(n0 + row, N_NODES - 1);
        const uint4 v = *((const uint4*)(hbf + (size_t)node * H) + c);
        *(uint4*)&A[row][c * 8] = v;
    }
    // stage agg (fp32 -> bf16) and re-zero owned rows (replaces next memset)
#pragma unroll
    for (int i = 0; i < 8; ++i) {
        const int f = tid + i * 256;
        const int row = f >> 5, c4 = f & 31;
        const int node = min(n0 + row, N_NODES - 1);
        float4* ap = (float4*)(agg + (size_t)node * H) + c4;
        const float4 v = *ap;
        if (n0 + row < N_NODES) {
            const float4 z = {0.f, 0.f, 0.f, 0.f};
            *ap = z;
        }
        unsigned short o[4] = { f2bf(v.x), f2bf(v.y), f2bf(v.z), f2bf(v.w) };
        *(uint2*)&A[row][128 + c4 * 4] = *(const uint2*)o;
    }
    __syncthreads();

    f32x4 acc[4][2];
#pragma unroll
    for (int mt = 0; mt < 4; ++mt) { acc[mt][0] = (f32x4)0.f; acc[mt][1] = (f32x4)0.f; }

#pragma unroll
    for (int kt = 0; kt < 8; ++kt) {
#pragma unroll
        for (int mt = 0; mt < 4; ++mt) {
            const s16x8 a = *(const s16x8*)&A[mt * 16 + l15][kt * 32 + l4 * 8];
            acc[mt][0] = __builtin_amdgcn_mfma_f32_16x16x32_bf16(a, bf0[kt], acc[mt][0], 0, 0, 0);
            acc[mt][1] = __builtin_amdgcn_mfma_f32_16x16x32_bf16(a, bf1[kt], acc[mt][1], 0, 0, 0);
        }
    }
    __syncthreads();   // all A reads done before fp32 overlay

    {
        const float bi0 = b[colbase + l15], bi1 = b[colbase + 16 + l15];
#pragma unroll
        for (int mt = 0; mt < 4; ++mt)
#pragma unroll
            for (int r = 0; r < 4; ++r) {
                const int row = mt * 16 + l4 * 4 + r;
                Afp[row * FPS + colbase + l15]      = fmaxf(acc[mt][0][r] + bi0, 0.f);
                Afp[row * FPS + colbase + 16 + l15] = fmaxf(acc[mt][1][r] + bi1, 0.f);
            }
    }
    __syncthreads();

    // LN: wave handles 16 rows; residual re-read from L2-hot hbf
    const float g0 = g[lane],   g1 = g[64 + lane];
    const float l0 = bln[lane], l1 = bln[64 + lane];
    for (int q = 0; q < 16; ++q) {
        const int row = wave * 16 + q;
        const int n = n0 + row;
        if (n >= N_NODES) break;
        const float hr0 = bf2f(hbf[(size_t)n * H + lane]);
        const float hr1 = bf2f(hbf[(size_t)n * H + 64 + lane]);
        float v0 = Afp[row * FPS + lane]      + hr0;
        float v1 = Afp[row * FPS + 64 + lane] + hr1;
        float s = v0 + v1;
#pragma unroll
        for (int off = 32; off > 0; off >>= 1) s += __shfl_xor(s, off, 64);
        const float mu = s * (1.f / 128.f);
        const float d0 = v0 - mu, d1 = v1 - mu;
        float vs = d0 * d0 + d1 * d1;
#pragma unroll
        for (int off = 32; off > 0; off >>= 1) vs += __shfl_xor(vs, off, 64);
        const float inv = rsqrtf(vs * (1.f / 128.f) + 1e-5f);
        hbf[(size_t)n * H + lane]      = f2bf(d0 * inv * g0 + l0);
        hbf[(size_t)n * H + 64 + lane] = f2bf(d1 * inv * g1 + l1);
    }
}

// ---------------------------------------------------------------------------
// final: out[c] = mean_n LN(hbf[n]; g,b)[c]
// ---------------------------------------------------------------------------
__global__ __launch_bounds__(256)
void final_kernel(const unsigned short* __restrict__ hbf,
                  const float* __restrict__ g, const float* __restrict__ b,
                  float* __restrict__ out)
{
    __shared__ float red[4][128];
    const int tid = threadIdx.x;
    const int wave = tid >> 6, lane = tid & 63;
    const float g0 = g[lane], g1 = g[64 + lane];
    const float b0 = b[lane], b1 = b[64 + lane];
    float a0 = 0.f, a1 = 0.f;

    for (int n = blockIdx.x * 4 + wave; n < N_NODES; n += gridDim.x * 4) {
        const float v0 = bf2f(hbf[(size_t)n * H + lane]);
        const float v1 = bf2f(hbf[(size_t)n * H + 64 + lane]);
        float s = v0 + v1;
#pragma unroll
        for (int off = 32; off > 0; off >>= 1) s += __shfl_xor(s, off, 64);
        const float mu = s * (1.f / 128.f);
        const float d0 = v0 - mu, d1 = v1 - mu;
        float vs = d0 * d0 + d1 * d1;
#pragma unroll
        for (int off = 32; off > 0; off >>= 1) vs += __shfl_xor(vs, off, 64);
        const float inv = rsqrtf(vs * (1.f / 128.f) + 1e-5f);
        a0 += d0 * inv * g0 + b0;
        a1 += d1 * inv * g1 + b1;
    }
    red[wave][lane]      = a0;
    red[wave][64 + lane] = a1;
    __syncthreads();
    if (wave == 0) {
        const float s0 = red[0][lane] + red[1][lane] + red[2][lane] + red[3][lane];
        const float s1 = red[0][64 + lane] + red[1][64 + lane] + red[2][64 + lane] + red[3][64 + lane];
        atomicAdd(&out[lane],      s0 * (1.f / N_NODES));
        atomicAdd(&out[64 + lane], s1 * (1.f / N_NODES));
    }
}

// ---------------------------------------------------------------------------
extern "C" void kernel_launch(void* const* d_in, const int* in_sizes, int n_in,
                              void* d_out, int out_size, void* d_ws, size_t ws_size,
                              hipStream_t stream)
{
    const float* x         = (const float*)d_in[0];
    const float* edge_attr = (const float*)d_in[1];
    const int*   edge_idx  = (const int*)  d_in[2];
    const float* proj_W    = (const float*)d_in[3];
    const float* proj_b    = (const float*)d_in[4];
    const float* msg_W1    = (const float*)d_in[5];
    const float* msg_b1    = (const float*)d_in[6];
    const float* msg_W2    = (const float*)d_in[7];
    const float* msg_b2    = (const float*)d_in[8];
    const float* upd_W     = (const float*)d_in[9];
    const float* upd_b     = (const float*)d_in[10];
    const float* ln_g      = (const float*)d_in[11];
    const float* ln_b      = (const float*)d_in[12];
    const float* out_g     = (const float*)d_in[13];
    const float* out_b     = (const float*)d_in[14];
    float* out = (float*)d_out;

    char* w = (char*)d_ws;
    float* agg = (float*)w;                   w += (size_t)N_NODES * H * 4;
    unsigned short* hbf  = (unsigned short*)w; w += (size_t)N_NODES * H * 2;
    unsigned short* eabf = (unsigned short*)w; w += (size_t)N_EDGES * E_DIM * 2;
    unsigned short* W1t  = (unsigned short*)w; w += (size_t)NLAYERS * H * K1P * 2;
    unsigned short* W2t  = (unsigned short*)w; w += (size_t)NLAYERS * H * H * 2;
    unsigned short* Wut  = (unsigned short*)w; w += (size_t)NLAYERS * H * 256 * 2;
    unsigned short* Wpt  = (unsigned short*)w; w += (size_t)H * DIM_IN * 2;
    int* hist   = (int*)w;                    w += (size_t)N_NODES * 4;
    int* cursor = (int*)w;                    w += (size_t)N_NODES * 4;
    int* i_s    = (int*)w;                    w += (size_t)N_EDGES * 4;
    int* j_s    = (int*)w;                    w += (size_t)N_EDGES * 4;
    int* perm   = (int*)w;                    w += (size_t)N_EDGES * 4;

    convert_w1<<<(NLAYERS * H * K1P) / 256, 256, 0, stream>>>(msg_W1, W1t);
    convert_w2<<<(NLAYERS * H * H) / 256, 256, 0, stream>>>(msg_W2, W2t);
    convert_wu<<<(NLAYERS * H * 256) / 256, 256, 0, stream>>>(upd_W, Wut);
    convert_wp<<<(H * DIM_IN) / 256, 256, 0, stream>>>(proj_W, Wpt);

    hipMemsetAsync(hist, 0, (size_t)N_NODES * 4, stream);
    hipMemsetAsync(agg, 0, (size_t)N_NODES * H * sizeof(float), stream);  // once; update re-zeroes
    hist_kernel<<<(N_EDGES + 255) / 256, 256, 0, stream>>>(edge_idx, hist);
    scan_kernel<<<1, 256, 0, stream>>>(hist, cursor);
    scatter_kernel<<<(N_EDGES + 255) / 256, 256, 0, stream>>>(edge_idx, cursor, i_s, j_s, perm);
    convert_ea<<<(N_EDGES * 8) / 256, 256, 0, stream>>>(edge_attr, perm, eabf);

    proj_mfma<<<(N_NODES + MB - 1) / MB, 256, 0, stream>>>(x, Wpt, proj_b, hbf);

    const int ublk = (N_NODES + UMB - 1) / UMB;
    for (int l = 0; l < NLAYERS; ++l) {
        edge_kernel<<<1024, 256, 0, stream>>>(
            hbf, eabf, i_s, j_s,
            W1t + (size_t)l * H * K1P, msg_b1 + (size_t)l * H,
            W2t + (size_t)l * H * H,   msg_b2 + (size_t)l * H, agg);
        update_mfma<<<ublk, 256, 0, stream>>>(
            hbf, agg, Wut + (size_t)l * H * 256, upd_b + (size_t)l * H,
            ln_g + (size_t)l * H, ln_b + (size_t)l * H);
    }

    hipMemsetAsync(out, 0, H * sizeof(float), stream);
    final_kernel<<<256, 256, 0, stream>>>(hbf, out_g, out_b, out);
}

// Round 12
// 625.176 us; speedup vs baseline: 1.8941x; 1.2728x over previous
//
#include <hip/hip_runtime.h>
#include <math.h>

#define N_NODES 50000
#define N_EDGES 400000
#define DIM_IN  128
#define H       128
#define E_DIM   16
#define NLAYERS 3

#define K1      272        // 2H + E_DIM
#define K1P     288        // padded to multiple of 32
#define HS      136        // hid/m tile row stride (shorts)
#define GS      136        // gather-sum tile row stride (shorts)
#define ES      40         // e-attr tile row stride (shorts), K=32 window
#define US      264        // update A-tile row stride (shorts)
#define PS      136        // proj/premul A-tile row stride (shorts)
#define FPS     132        // fp32 LDS row stride (floats), update epilogue
#define MB      32         // rows per tile
#define UMB     64         // rows per update block
#define NT_E    (N_EDGES / MB)   // 12500 edge tiles

typedef short  s16x8 __attribute__((ext_vector_type(8)));
typedef float  f32x4 __attribute__((ext_vector_type(4)));

__device__ inline unsigned short f2bf(float f) {
    union { float f; unsigned u; } v; v.f = f;
    unsigned r = v.u + 0x7FFFu + ((v.u >> 16) & 1u);
    return (unsigned short)(r >> 16);
}
__device__ inline float bf2f(unsigned short u) {
    union { unsigned u; float f; } v; v.u = (unsigned)u << 16; return v.f;
}
__device__ inline uint4 addbf8(uint4 a, uint4 b) {
    union U { uint4 v; unsigned short s[8]; } ua, ub, uo;
    ua.v = a; ub.v = b;
#pragma unroll
    for (int i = 0; i < 8; ++i) uo.s[i] = f2bf(bf2f(ua.s[i]) + bf2f(ub.s[i]));
    return uo.v;
}

// ---------------------------------------------------------------------------
// weight convert/transpose kernels (tiny, once per launch)
// ---------------------------------------------------------------------------
__global__ __launch_bounds__(256)
void convert_w1(const float* __restrict__ W1, unsigned short* __restrict__ W1t)
{   // [L][272][128] f32 -> [L][128][288] bf16 (zero pad)
    const int o = blockIdx.x * 256 + threadIdx.x;
    const int l = o / (128 * K1P);
    const int r = o % (128 * K1P);
    const int n = r / K1P;
    const int k = r % K1P;
    const float v = (k < K1) ? W1[(size_t)l * K1 * H + (size_t)k * H + n] : 0.f;
    W1t[o] = f2bf(v);
}

__global__ __launch_bounds__(256)
void convert_w2(const float* __restrict__ W2, unsigned short* __restrict__ W2t)
{   // [L][128][128] -> transposed bf16
    const int o = blockIdx.x * 256 + threadIdx.x;
    const int l = o / (H * H);
    const int r = o % (H * H);
    const int n = r / H;
    const int k = r % H;
    W2t[o] = f2bf(W2[(size_t)l * H * H + (size_t)k * H + n]);
}

__global__ __launch_bounds__(256)
void convert_wu(const float* __restrict__ Wu, unsigned short* __restrict__ Wut)
{   // [L][256][128] -> [L][128][256] bf16
    const int o = blockIdx.x * 256 + threadIdx.x;
    const int l = o / (H * 256);
    const int r = o % (H * 256);
    const int n = r / 256;
    const int k = r % 256;
    Wut[o] = f2bf(Wu[(size_t)l * 256 * H + (size_t)k * H + n]);
}

__global__ __launch_bounds__(256)
void convert_wp(const float* __restrict__ Wp, unsigned short* __restrict__ Wpt)
{   // [128][128] -> transposed bf16
    const int o = blockIdx.x * 256 + threadIdx.x;
    const int n = o / H;
    const int k = o % H;
    Wpt[o] = f2bf(Wp[(size_t)k * H + n]);
}

// edge_attr -> bf16 in sorted order
__global__ __launch_bounds__(256)
void convert_ea(const float* __restrict__ ea, const int* __restrict__ perm,
                unsigned short* __restrict__ eabf)
{
    const int o = blockIdx.x * 256 + threadIdx.x;
    const int p = o >> 3;
    const int j = (o & 7) * 2;
    const int pe = perm[p];
    const float2 v = *(const float2*)&ea[(size_t)pe * E_DIM + j];
    eabf[(size_t)p * E_DIM + j]     = f2bf(v.x);
    eabf[(size_t)p * E_DIM + j + 1] = f2bf(v.y);
}

// ---------------------------------------------------------------------------
// counting sort of edges by destination (i_idx)
// ---------------------------------------------------------------------------
__global__ __launch_bounds__(256)
void hist_kernel(const int* __restrict__ ei, int* __restrict__ hist)
{
    const int e = blockIdx.x * 256 + threadIdx.x;
    if (e < N_EDGES) atomicAdd(&hist[ei[e]], 1);
}

__global__ __launch_bounds__(256)
void scan_kernel(const int* __restrict__ hist, int* __restrict__ cursor)
{
    __shared__ int ps[256];
    const int t = threadIdx.x;
    const int CH = 196;
    const int base = t * CH;
    int s = 0;
    for (int i = 0; i < CH; ++i) { const int idx = base + i; if (idx < N_NODES) s += hist[idx]; }
    ps[t] = s; __syncthreads();
    for (int off = 1; off < 256; off <<= 1) {
        const int v = (t >= off) ? ps[t - off] : 0;
        __syncthreads();
        ps[t] += v;
        __syncthreads();
    }
    int run = (t > 0) ? ps[t - 1] : 0;
    for (int i = 0; i < CH; ++i) {
        const int idx = base + i;
        if (idx < N_NODES) { cursor[idx] = run; run += hist[idx]; }
    }
}

__global__ __launch_bounds__(256)
void scatter_kernel(const int* __restrict__ ei, int* __restrict__ cursor,
                    int* __restrict__ i_s, int* __restrict__ j_s, int* __restrict__ perm)
{
    const int e = blockIdx.x * 256 + threadIdx.x;
    if (e < N_EDGES) {
        const int d = ei[e];
        const int p = atomicAdd(&cursor[d], 1);
        i_s[p] = d;
        j_s[p] = ei[N_EDGES + e];
        perm[p] = e;
    }
}

// ---------------------------------------------------------------------------
// proj (MFMA): hbf = bf16(x @ Wp + b)
// ---------------------------------------------------------------------------
__global__ __launch_bounds__(256)
void proj_mfma(const float* __restrict__ x, const unsigned short* __restrict__ Wpt,
               const float* __restrict__ b, unsigned short* __restrict__ hbf)
{
    __shared__ __align__(16) unsigned short A[MB][PS];
    const int tid = threadIdx.x;
    const int n0 = blockIdx.x * MB;
    const int wave = tid >> 6, lane = tid & 63, l15 = lane & 15, l4 = lane >> 4;
    const int colbase = wave * 32;

#pragma unroll
    for (int i = 0; i < 4; ++i) {
        const int f = tid + i * 256;
        const int row = f >> 5, c4 = f & 31;
        const int node = min(n0 + row, N_NODES - 1);
        const float4 v = *((const float4*)(x + (size_t)node * DIM_IN) + c4);
        unsigned short o[4] = { f2bf(v.x), f2bf(v.y), f2bf(v.z), f2bf(v.w) };
        *(uint2*)&A[row][c4 * 4] = *(const uint2*)o;
    }
    __syncthreads();

    f32x4 acc[2][2];
#pragma unroll
    for (int mt = 0; mt < 2; ++mt)
#pragma unroll
        for (int nt = 0; nt < 2; ++nt) acc[mt][nt] = (f32x4)0.f;

    for (int k = 0; k < DIM_IN; k += 32) {
        const s16x8 a0 = *(const s16x8*)&A[l15][k + l4 * 8];
        const s16x8 a1 = *(const s16x8*)&A[16 + l15][k + l4 * 8];
        const s16x8 b0 = *(const s16x8*)&Wpt[(size_t)(colbase + l15) * DIM_IN + k + l4 * 8];
        const s16x8 b1 = *(const s16x8*)&Wpt[(size_t)(colbase + 16 + l15) * DIM_IN + k + l4 * 8];
        acc[0][0] = __builtin_amdgcn_mfma_f32_16x16x32_bf16(a0, b0, acc[0][0], 0, 0, 0);
        acc[0][1] = __builtin_amdgcn_mfma_f32_16x16x32_bf16(a0, b1, acc[0][1], 0, 0, 0);
        acc[1][0] = __builtin_amdgcn_mfma_f32_16x16x32_bf16(a1, b0, acc[1][0], 0, 0, 0);
        acc[1][1] = __builtin_amdgcn_mfma_f32_16x16x32_bf16(a1, b1, acc[1][1], 0, 0, 0);
    }

    const float bi0 = b[colbase + l15], bi1 = b[colbase + 16 + l15];
#pragma unroll
    for (int mt = 0; mt < 2; ++mt)
#pragma unroll
        for (int r = 0; r < 4; ++r) {
            const int row = mt * 16 + l4 * 4 + r;
            const int n = n0 + row;
            if (n < N_NODES) {
                hbf[(size_t)n * H + colbase + l15]      = f2bf(acc[mt][0][r] + bi0);
                hbf[(size_t)n * H + colbase + 16 + l15] = f2bf(acc[mt][1][r] + bi1);
            }
        }
}

// ---------------------------------------------------------------------------
// premul: Pa = bf16(h @ W1a), Pb = bf16(h @ W1b)  — dense, coalesced.
// W1a = W1 rows 0..127 (h_i part), W1b = rows 128..255 (h_j part); frags
// read from W1t [128][288] at k-offsets 0 and 128.
// ---------------------------------------------------------------------------
__global__ __launch_bounds__(256)
void premul(const unsigned short* __restrict__ hbf,
            const unsigned short* __restrict__ W1t,
            unsigned short* __restrict__ Pa, unsigned short* __restrict__ Pb)
{
    __shared__ __align__(16) unsigned short A[MB][PS];
    const int tid = threadIdx.x;
    const int n0 = blockIdx.x * MB;
    const int wave = tid >> 6, lane = tid & 63, l15 = lane & 15, l4 = lane >> 4;
    const int colbase = wave * 32;

#pragma unroll
    for (int i = 0; i < 2; ++i) {
        const int f = tid + i * 256;
        const int row = f >> 4, c = f & 15;
        const int node = min(n0 + row, N_NODES - 1);
        const uint4 v = *((const uint4*)(hbf + (size_t)node * H) + c);
        *(uint4*)&A[row][c * 8] = v;
    }
    __syncthreads();

    f32x4 aa[2][2], ab[2][2];
#pragma unroll
    for (int mt = 0; mt < 2; ++mt)
#pragma unroll
        for (int nt = 0; nt < 2; ++nt) { aa[mt][nt] = (f32x4)0.f; ab[mt][nt] = (f32x4)0.f; }

#pragma unroll
    for (int kt = 0; kt < 4; ++kt) {
        const s16x8 a0 = *(const s16x8*)&A[l15][kt * 32 + l4 * 8];
        const s16x8 a1 = *(const s16x8*)&A[16 + l15][kt * 32 + l4 * 8];
        const s16x8 wa0 = *(const s16x8*)&W1t[(size_t)(colbase + l15) * K1P + kt * 32 + l4 * 8];
        const s16x8 wa1 = *(const s16x8*)&W1t[(size_t)(colbase + 16 + l15) * K1P + kt * 32 + l4 * 8];
        const s16x8 wb0 = *(const s16x8*)&W1t[(size_t)(colbase + l15) * K1P + 128 + kt * 32 + l4 * 8];
        const s16x8 wb1 = *(const s16x8*)&W1t[(size_t)(colbase + 16 + l15) * K1P + 128 + kt * 32 + l4 * 8];
        aa[0][0] = __builtin_amdgcn_mfma_f32_16x16x32_bf16(a0, wa0, aa[0][0], 0, 0, 0);
        aa[0][1] = __builtin_amdgcn_mfma_f32_16x16x32_bf16(a0, wa1, aa[0][1], 0, 0, 0);
        aa[1][0] = __builtin_amdgcn_mfma_f32_16x16x32_bf16(a1, wa0, aa[1][0], 0, 0, 0);
        aa[1][1] = __builtin_amdgcn_mfma_f32_16x16x32_bf16(a1, wa1, aa[1][1], 0, 0, 0);
        ab[0][0] = __builtin_amdgcn_mfma_f32_16x16x32_bf16(a0, wb0, ab[0][0], 0, 0, 0);
        ab[0][1] = __builtin_amdgcn_mfma_f32_16x16x32_bf16(a0, wb1, ab[0][1], 0, 0, 0);
        ab[1][0] = __builtin_amdgcn_mfma_f32_16x16x32_bf16(a1, wb0, ab[1][0], 0, 0, 0);
        ab[1][1] = __builtin_amdgcn_mfma_f32_16x16x32_bf16(a1, wb1, ab[1][1], 0, 0, 0);
    }

#pragma unroll
    for (int mt = 0; mt < 2; ++mt)
#pragma unroll
        for (int r = 0; r < 4; ++r) {
            const int row = mt * 16 + l4 * 4 + r;
            const int n = n0 + row;
            if (n < N_NODES) {
                Pa[(size_t)n * H + colbase + l15]      = f2bf(aa[mt][0][r]);
                Pa[(size_t)n * H + colbase + 16 + l15] = f2bf(aa[mt][1][r]);
                Pb[(size_t)n * H + colbase + l15]      = f2bf(ab[mt][0][r]);
                Pb[(size_t)n * H + colbase + 16 + l15] = f2bf(ab[mt][1][r]);
            }
        }
}

// ---------------------------------------------------------------------------
// edge kernel v2: no GEMM1. Per 32-edge tile: gather Pa[i]+Pb[j] (reg add ->
// Gsum LDS), e@W1c via single-ktile MFMA (frags from W1t k=256..287,
// zero-padded), hid = relu(eterm + Gsum + b1), GEMM2, pure-atomic 16-row
// segment reduce. 2 barriers/tile, register prefetch. ~29 KB LDS, low VGPR.
// ---------------------------------------------------------------------------
__global__ __launch_bounds__(256, 4)
void edge_kernel(const unsigned short* __restrict__ Pa,
                 const unsigned short* __restrict__ Pb,
                 const unsigned short* __restrict__ eabf,  // [E][16] bf16, sorted
                 const int*   __restrict__ i_s,
                 const int*   __restrict__ j_s,
                 const unsigned short* __restrict__ W1t,   // [128][288] (W1c at k=256..287)
                 const float* __restrict__ b1,
                 const unsigned short* __restrict__ W2t,   // [128][128]
                 const float* __restrict__ b2,
                 float*       __restrict__ agg)
{
    __shared__ __align__(16) unsigned short Gsum[MB * GS];  // 8704 B
    __shared__ __align__(16) unsigned short Et[MB * ES];    // 2560 B
    __shared__ __align__(16) unsigned short Hid[MB * HS];   // 8704 B
    __shared__ __align__(16) unsigned short Mbf[MB * HS];   // 8704 B
    __shared__ int idxbuf[2][MB];                           //  256 B

    const int tid  = threadIdx.x;
    const int wave = tid >> 6;
    const int lane = tid & 63;
    const int l15  = lane & 15;
    const int l4   = lane >> 4;
    const int colbase = wave * 32;

    // slot roles: slot s = tid + i*256 (i=0,1): e = s>>4 (0..31), ch = s&15
    const int sl_e = tid >> 4;          // edge for slot i: sl_e + i*16
    const int sl_c = tid & 15;          // uint4 chunk within row

    // weights in registers: W2 frags (32 VGPR) + W1c frags (8 VGPR)
    s16x8 w2f[2][4], w1cf[2];
#pragma unroll
    for (int kt = 0; kt < 4; ++kt) {
        w2f[0][kt] = *(const s16x8*)&W2t[(size_t)(colbase + l15) * H + kt * 32 + l4 * 8];
        w2f[1][kt] = *(const s16x8*)&W2t[(size_t)(colbase + 16 + l15) * H + kt * 32 + l4 * 8];
    }
    w1cf[0] = *(const s16x8*)&W1t[(size_t)(colbase + l15) * K1P + 256 + l4 * 8];
    w1cf[1] = *(const s16x8*)&W1t[(size_t)(colbase + 16 + l15) * K1P + 256 + l4 * 8];
    const float b1c0 = b1[colbase + l15], b1c1 = b1[colbase + 16 + l15];
    const float b2c0 = b2[colbase + l15], b2c1 = b2[colbase + 16 + l15];

    int t = blockIdx.x;
    if (t >= NT_E) return;

    // ---- prologue: stage tile t
    {
#pragma unroll
        for (int i = 0; i < 2; ++i) {
            const int e = sl_e + i * 16;
            const int ni = i_s[t * MB + e];
            const int nj = j_s[t * MB + e];
            const uint4 va = *((const uint4*)(Pa + (size_t)ni * H) + sl_c);
            const uint4 vb = *((const uint4*)(Pb + (size_t)nj * H) + sl_c);
            *(uint4*)&Gsum[e * GS + sl_c * 8] = addbf8(va, vb);
        }
        if (tid < 64) {
            const uint4 ve = *((const uint4*)eabf + (size_t)t * 64 + tid);
            *(uint4*)&Et[(tid >> 1) * ES + (tid & 1) * 8] = ve;
        } else if (tid < 128) {
            const int tt = tid - 64;
            const uint4 z = {0, 0, 0, 0};
            *(uint4*)&Et[(tt >> 1) * ES + 16 + (tt & 1) * 8] = z;   // pad stays zero
        }
        if (tid < MB) idxbuf[0][tid] = i_s[t * MB + tid];
    }
    __syncthreads();

    int p = 0;
    for (; t < NT_E; t += gridDim.x, p ^= 1) {
        const int t1 = t + gridDim.x;

        // ---- 1. prefetch next tile into registers
        uint4 pfa[2], pfb[2];
        uint4 pfe = {0, 0, 0, 0};
        int   pfi = 0;
        if (t1 < NT_E) {
#pragma unroll
            for (int i = 0; i < 2; ++i) {
                const int e = sl_e + i * 16;
                const int ni = i_s[t1 * MB + e];
                const int nj = j_s[t1 * MB + e];
                pfa[i] = *((const uint4*)(Pa + (size_t)ni * H) + sl_c);
                pfb[i] = *((const uint4*)(Pb + (size_t)nj * H) + sl_c);
            }
            if (tid < 64) pfe = *((const uint4*)eabf + (size_t)t1 * 64 + tid);
            if (tid < MB) pfi = i_s[t1 * MB + tid];
        }

        // ---- 2. e-term MFMA (single ktile, K=32 w/ zero pad)
        f32x4 acc[2][2];
#pragma unroll
        for (int mt = 0; mt < 2; ++mt)
#pragma unroll
            for (int nt = 0; nt < 2; ++nt) acc[mt][nt] = (f32x4)0.f;
        {
            const s16x8 a0 = *(const s16x8*)&Et[l15 * ES + l4 * 8];
            const s16x8 a1 = *(const s16x8*)&Et[(16 + l15) * ES + l4 * 8];
            acc[0][0] = __builtin_amdgcn_mfma_f32_16x16x32_bf16(a0, w1cf[0], acc[0][0], 0, 0, 0);
            acc[0][1] = __builtin_amdgcn_mfma_f32_16x16x32_bf16(a0, w1cf[1], acc[0][1], 0, 0, 0);
            acc[1][0] = __builtin_amdgcn_mfma_f32_16x16x32_bf16(a1, w1cf[0], acc[1][0], 0, 0, 0);
            acc[1][1] = __builtin_amdgcn_mfma_f32_16x16x32_bf16(a1, w1cf[1], acc[1][1], 0, 0, 0);
        }

        // ---- 3. hid = relu(eterm + Gsum + b1) -> Hid
#pragma unroll
        for (int mt = 0; mt < 2; ++mt)
#pragma unroll
            for (int r = 0; r < 4; ++r) {
                const int row = mt * 16 + l4 * 4 + r;
                const float g0 = bf2f(Gsum[row * GS + colbase + l15]);
                const float g1 = bf2f(Gsum[row * GS + colbase + 16 + l15]);
                Hid[row * HS + colbase + l15]      = f2bf(fmaxf(acc[mt][0][r] + g0 + b1c0, 0.f));
                Hid[row * HS + colbase + 16 + l15] = f2bf(fmaxf(acc[mt][1][r] + g1 + b1c1, 0.f));
            }
        __syncthreads();             // barrier A: Gsum/Et reads done, Hid ready

        // ---- 4. drain prefetch: add Pa+Pb -> Gsum; Et; idxbuf[p^1]
        if (t1 < NT_E) {
#pragma unroll
            for (int i = 0; i < 2; ++i) {
                const int e = sl_e + i * 16;
                *(uint4*)&Gsum[e * GS + sl_c * 8] = addbf8(pfa[i], pfb[i]);
            }
            if (tid < 64)
                *(uint4*)&Et[(tid >> 1) * ES + (tid & 1) * 8] = pfe;
            if (tid < MB) idxbuf[p ^ 1][tid] = pfi;
        }

        // ---- 5. GEMM2: Hid[32x128] x W2 -> acc
#pragma unroll
        for (int mt = 0; mt < 2; ++mt)
#pragma unroll
            for (int nt = 0; nt < 2; ++nt) acc[mt][nt] = (f32x4)0.f;

#pragma unroll
        for (int kt = 0; kt < 4; ++kt) {
            const s16x8 a0 = *(const s16x8*)&Hid[l15 * HS + kt * 32 + l4 * 8];
            const s16x8 a1 = *(const s16x8*)&Hid[(16 + l15) * HS + kt * 32 + l4 * 8];
            acc[0][0] = __builtin_amdgcn_mfma_f32_16x16x32_bf16(a0, w2f[0][kt], acc[0][0], 0, 0, 0);
            acc[0][1] = __builtin_amdgcn_mfma_f32_16x16x32_bf16(a0, w2f[1][kt], acc[0][1], 0, 0, 0);
            acc[1][0] = __builtin_amdgcn_mfma_f32_16x16x32_bf16(a1, w2f[0][kt], acc[1][0], 0, 0, 0);
            acc[1][1] = __builtin_amdgcn_mfma_f32_16x16x32_bf16(a1, w2f[1][kt], acc[1][1], 0, 0, 0);
        }

        // ---- 6. m = relu(acc+b2) -> Mbf
#pragma unroll
        for (int mt = 0; mt < 2; ++mt)
#pragma unroll
            for (int r = 0; r < 4; ++r) {
                const int row = mt * 16 + l4 * 4 + r;
                Mbf[row * HS + colbase + l15]      = f2bf(fmaxf(acc[mt][0][r] + b2c0, 0.f));
                Mbf[row * HS + colbase + 16 + l15] = f2bf(fmaxf(acc[mt][1][r] + b2c1, 0.f));
            }
        __syncthreads();             // barrier B: Mbf ready, next tile staged

        // ---- 7. 16-row segment reduce, pure atomics (R6-proven)
        {
            const int* idxp = idxbuf[p];
            const int c    = tid & 127;
            const int half = tid >> 7;
            int cur = idxp[half * 16];
            float s = 0.f;
            for (int r = half * 16; r < half * 16 + 16; ++r) {
                const int d = idxp[r];
                if (d != cur) {
                    atomicAdd(&agg[(size_t)cur * H + c], s);
                    s = 0.f; cur = d;
                }
                s += bf2f(Mbf[r * HS + c]);
            }
            atomicAdd(&agg[(size_t)cur * H + c], s);
        }
        // reduce(k) reads Mbf/idxbuf[p]; next writers gated by barrier A(k+1).
    }
}

// ---------------------------------------------------------------------------
// node update (MFMA, 64 rows/block): out = relu([h,agg]Wu+b);
// hbf = bf16(LN(out+h)); agg rows re-zeroed for next layer (replaces memset).
// ---------------------------------------------------------------------------
__global__ __launch_bounds__(256, 3)
void update_mfma(unsigned short* __restrict__ hbf, float* __restrict__ agg,
                 const unsigned short* __restrict__ Wut, const float* __restrict__ b,
                 const float* __restrict__ g, const float* __restrict__ bln)
{
    __shared__ __align__(16) unsigned short A[UMB][US];  // 33792 B
    float* Afp = (float*)&A[0][0];                       // [64][FPS] overlay

    const int tid = threadIdx.x;
    const int n0 = blockIdx.x * UMB;
    const int wave = tid >> 6, lane = tid & 63, l15 = lane & 15, l4 = lane >> 4;
    const int colbase = wave * 32;

    s16x8 bf0[8], bf1[8];
#pragma unroll
    for (int kt = 0; kt < 8; ++kt) {
        bf0[kt] = *(const s16x8*)&Wut[(size_t)(colbase + l15) * 256 + kt * 32 + l4 * 8];
        bf1[kt] = *(const s16x8*)&Wut[(size_t)(colbase + 16 + l15) * 256 + kt * 32 + l4 * 8];
    }

#pragma unroll
    for (int i = 0; i < 4; ++i) {
        const int f = tid + i * 256;
        const int row = f >> 4, c = f & 15;
        const int node = min(n0 + row, N_NODES - 1);
        const uint4 v = *((const uint4*)(hbf + (size_t)node * H) + c);
        *(uint4*)&A[row][c * 8] = v;
    }
#pragma unroll
    for (int i = 0; i < 8; ++i) {
        const int f = tid + i * 256;
        const int row = f >> 5, c4 = f & 31;
        const int node = min(n0 + row, N_NODES - 1);
        float4* ap = (float4*)(agg + (size_t)node * H) + c4;
        const float4 v = *ap;
        if (n0 + row < N_NODES) {
            const float4 z = {0.f, 0.f, 0.f, 0.f};
            *ap = z;
        }
        unsigned short o[4] = { f2bf(v.x), f2bf(v.y), f2bf(v.z), f2bf(v.w) };
        *(uint2*)&A[row][128 + c4 * 4] = *(const uint2*)o;
    }
    __syncthreads();

    f32x4 acc[4][2];
#pragma unroll
    for (int mt = 0; mt < 4; ++mt) { acc[mt][0] = (f32x4)0.f; acc[mt][1] = (f32x4)0.f; }

#pragma unroll
    for (int kt = 0; kt < 8; ++kt) {
#pragma unroll
        for (int mt = 0; mt < 4; ++mt) {
            const s16x8 a = *(const s16x8*)&A[mt * 16 + l15][kt * 32 + l4 * 8];
            acc[mt][0] = __builtin_amdgcn_mfma_f32_16x16x32_bf16(a, bf0[kt], acc[mt][0], 0, 0, 0);
            acc[mt][1] = __builtin_amdgcn_mfma_f32_16x16x32_bf16(a, bf1[kt], acc[mt][1], 0, 0, 0);
        }
    }
    __syncthreads();

    {
        const float bi0 = b[colbase + l15], bi1 = b[colbase + 16 + l15];
#pragma unroll
        for (int mt = 0; mt < 4; ++mt)
#pragma unroll
            for (int r = 0; r < 4; ++r) {
                const int row = mt * 16 + l4 * 4 + r;
                Afp[row * FPS + colbase + l15]      = fmaxf(acc[mt][0][r] + bi0, 0.f);
                Afp[row * FPS + colbase + 16 + l15] = fmaxf(acc[mt][1][r] + bi1, 0.f);
            }
    }
    __syncthreads();

    const float g0 = g[lane],   g1 = g[64 + lane];
    const float l0 = bln[lane], l1 = bln[64 + lane];
    for (int q = 0; q < 16; ++q) {
        const int row = wave * 16 + q;
        const int n = n0 + row;
        if (n >= N_NODES) break;
        const float hr0 = bf2f(hbf[(size_t)n * H + lane]);
        const float hr1 = bf2f(hbf[(size_t)n * H + 64 + lane]);
        float v0 = Afp[row * FPS + lane]      + hr0;
        float v1 = Afp[row * FPS + 64 + lane] + hr1;
        float s = v0 + v1;
#pragma unroll
        for (int off = 32; off > 0; off >>= 1) s += __shfl_xor(s, off, 64);
        const float mu = s * (1.f / 128.f);
        const float d0 = v0 - mu, d1 = v1 - mu;
        float vs = d0 * d0 + d1 * d1;
#pragma unroll
        for (int off = 32; off > 0; off >>= 1) vs += __shfl_xor(vs, off, 64);
        const float inv = rsqrtf(vs * (1.f / 128.f) + 1e-5f);
        hbf[(size_t)n * H + lane]      = f2bf(d0 * inv * g0 + l0);
        hbf[(size_t)n * H + 64 + lane] = f2bf(d1 * inv * g1 + l1);
    }
}

// ---------------------------------------------------------------------------
// final: out[c] = mean_n LN(hbf[n]; g,b)[c]
// ---------------------------------------------------------------------------
__global__ __launch_bounds__(256)
void final_kernel(const unsigned short* __restrict__ hbf,
                  const float* __restrict__ g, const float* __restrict__ b,
                  float* __restrict__ out)
{
    __shared__ float red[4][128];
    const int tid = threadIdx.x;
    const int wave = tid >> 6, lane = tid & 63;
    const float g0 = g[lane], g1 = g[64 + lane];
    const float b0 = b[lane], b1 = b[64 + lane];
    float a0 = 0.f, a1 = 0.f;

    for (int n = blockIdx.x * 4 + wave; n < N_NODES; n += gridDim.x * 4) {
        const float v0 = bf2f(hbf[(size_t)n * H + lane]);
        const float v1 = bf2f(hbf[(size_t)n * H + 64 + lane]);
        float s = v0 + v1;
#pragma unroll
        for (int off = 32; off > 0; off >>= 1) s += __shfl_xor(s, off, 64);
        const float mu = s * (1.f / 128.f);
        const float d0 = v0 - mu, d1 = v1 - mu;
        float vs = d0 * d0 + d1 * d1;
#pragma unroll
        for (int off = 32; off > 0; off >>= 1) vs += __shfl_xor(vs, off, 64);
        const float inv = rsqrtf(vs * (1.f / 128.f) + 1e-5f);
        a0 += d0 * inv * g0 + b0;
        a1 += d1 * inv * g1 + b1;
    }
    red[wave][lane]      = a0;
    red[wave][64 + lane] = a1;
    __syncthreads();
    if (wave == 0) {
        const float s0 = red[0][lane] + red[1][lane] + red[2][lane] + red[3][lane];
        const float s1 = red[0][64 + lane] + red[1][64 + lane] + red[2][64 + lane] + red[3][64 + lane];
        atomicAdd(&out[lane],      s0 * (1.f / N_NODES));
        atomicAdd(&out[64 + lane], s1 * (1.f / N_NODES));
    }
}

// ---------------------------------------------------------------------------
extern "C" void kernel_launch(void* const* d_in, const int* in_sizes, int n_in,
                              void* d_out, int out_size, void* d_ws, size_t ws_size,
                              hipStream_t stream)
{
    const float* x         = (const float*)d_in[0];
    const float* edge_attr = (const float*)d_in[1];
    const int*   edge_idx  = (const int*)  d_in[2];
    const float* proj_W    = (const float*)d_in[3];
    const float* proj_b    = (const float*)d_in[4];
    const float* msg_W1    = (const float*)d_in[5];
    const float* msg_b1    = (const float*)d_in[6];
    const float* msg_W2    = (const float*)d_in[7];
    const float* msg_b2    = (const float*)d_in[8];
    const float* upd_W     = (const float*)d_in[9];
    const float* upd_b     = (const float*)d_in[10];
    const float* ln_g      = (const float*)d_in[11];
    const float* ln_b      = (const float*)d_in[12];
    const float* out_g     = (const float*)d_in[13];
    const float* out_b     = (const float*)d_in[14];
    float* out = (float*)d_out;

    char* w = (char*)d_ws;
    float* agg = (float*)w;                   w += (size_t)N_NODES * H * 4;
    unsigned short* hbf  = (unsigned short*)w; w += (size_t)N_NODES * H * 2;
    unsigned short* Pa   = (unsigned short*)w; w += (size_t)N_NODES * H * 2;
    unsigned short* Pb   = (unsigned short*)w; w += (size_t)N_NODES * H * 2;
    unsigned short* eabf = (unsigned short*)w; w += (size_t)N_EDGES * E_DIM * 2;
    unsigned short* W1t  = (unsigned short*)w; w += (size_t)NLAYERS * H * K1P * 2;
    unsigned short* W2t  = (unsigned short*)w; w += (size_t)NLAYERS * H * H * 2;
    unsigned short* Wut  = (unsigned short*)w; w += (size_t)NLAYERS * H * 256 * 2;
    unsigned short* Wpt  = (unsigned short*)w; w += (size_t)H * DIM_IN * 2;
    int* hist   = (int*)w;                    w += (size_t)N_NODES * 4;
    int* cursor = (int*)w;                    w += (size_t)N_NODES * 4;
    int* i_s    = (int*)w;                    w += (size_t)N_EDGES * 4;
    int* j_s    = (int*)w;                    w += (size_t)N_EDGES * 4;
    int* perm   = (int*)w;                    w += (size_t)N_EDGES * 4;

    convert_w1<<<(NLAYERS * H * K1P) / 256, 256, 0, stream>>>(msg_W1, W1t);
    convert_w2<<<(NLAYERS * H * H) / 256, 256, 0, stream>>>(msg_W2, W2t);
    convert_wu<<<(NLAYERS * H * 256) / 256, 256, 0, stream>>>(upd_W, Wut);
    convert_wp<<<(H * DIM_IN) / 256, 256, 0, stream>>>(proj_W, Wpt);

    hipMemsetAsync(hist, 0, (size_t)N_NODES * 4, stream);
    hipMemsetAsync(agg, 0, (size_t)N_NODES * H * sizeof(float), stream);  // once; update re-zeroes
    hist_kernel<<<(N_EDGES + 255) / 256, 256, 0, stream>>>(edge_idx, hist);
    scan_kernel<<<1, 256, 0, stream>>>(hist, cursor);
    scatter_kernel<<<(N_EDGES + 255) / 256, 256, 0, stream>>>(edge_idx, cursor, i_s, j_s, perm);
    convert_ea<<<(N_EDGES * 8) / 256, 256, 0, stream>>>(edge_attr, perm, eabf);

    const int nblk = (N_NODES + MB - 1) / MB;
    proj_mfma<<<nblk, 256, 0, stream>>>(x, Wpt, proj_b, hbf);

    const int ublk = (N_NODES + UMB - 1) / UMB;
    for (int l = 0; l < NLAYERS; ++l) {
        premul<<<nblk, 256, 0, stream>>>(hbf, W1t + (size_t)l * H * K1P, Pa, Pb);
        edge_kernel<<<1024, 256, 0, stream>>>(
            Pa, Pb, eabf, i_s, j_s,
            W1t + (size_t)l * H * K1P, msg_b1 + (size_t)l * H,
            W2t + (size_t)l * H * H,   msg_b2 + (size_t)l * H, agg);
        update_mfma<<<ublk, 256, 0, stream>>>(
            hbf, agg, Wut + (size_t)l * H * 256, upd_b + (size_t)l * H,
            ln_g + (size_t)l * H, ln_b + (size_t)l * H);
    }

    hipMemsetAsync(out, 0, H * sizeof(float), stream);
    final_kernel<<<256, 256, 0, stream>>>(hbf, out_g, out_b, out);
}

// Round 13
// 534.436 us; speedup vs baseline: 2.2157x; 1.1698x over previous
//
#include <hip/hip_runtime.h>
#include <math.h>

#define N_NODES 50000
#define N_EDGES 400000
#define DIM_IN  128
#define H       128
#define E_DIM   16
#define NLAYERS 3

#define K1      272        // 2H + E_DIM
#define K1P     288        // padded to multiple of 32
#define HS      136        // hid/m tile row stride (shorts)
#define GS      136        // gather-sum tile row stride (shorts)
#define ES      40         // e-attr tile row stride (shorts), K=32 window
#define US      264        // update A-tile row stride (shorts)
#define PS      136        // proj/premul A-tile row stride (shorts)
#define FPS     132        // fp32 LDS row stride (floats), update epilogue
#define MB      32         // rows per tile
#define UMB     64         // rows per update block
#define NT_E    (N_EDGES / MB)   // 12500 edge tiles
#define NSB     ((N_NODES + 255) / 256)   // 196 scan blocks

typedef short  s16x8 __attribute__((ext_vector_type(8)));
typedef float  f32x4 __attribute__((ext_vector_type(4)));

__device__ inline unsigned short f2bf(float f) {
    union { float f; unsigned u; } v; v.f = f;
    unsigned r = v.u + 0x7FFFu + ((v.u >> 16) & 1u);
    return (unsigned short)(r >> 16);
}
__device__ inline float bf2f(unsigned short u) {
    union { unsigned u; float f; } v; v.u = (unsigned)u << 16; return v.f;
}
__device__ inline uint4 addbf8(uint4 a, uint4 b) {
    union U { uint4 v; unsigned short s[8]; } ua, ub, uo;
    ua.v = a; ub.v = b;
#pragma unroll
    for (int i = 0; i < 8; ++i) uo.s[i] = f2bf(bf2f(ua.s[i]) + bf2f(ub.s[i]));
    return uo.v;
}

// ---------------------------------------------------------------------------
// weight convert/transpose kernels (tiny, once per launch)
// ---------------------------------------------------------------------------
__global__ __launch_bounds__(256)
void convert_w1(const float* __restrict__ W1, unsigned short* __restrict__ W1t)
{   // [L][272][128] f32 -> [L][128][288] bf16 (zero pad)
    const int o = blockIdx.x * 256 + threadIdx.x;
    const int l = o / (128 * K1P);
    const int r = o % (128 * K1P);
    const int n = r / K1P;
    const int k = r % K1P;
    const float v = (k < K1) ? W1[(size_t)l * K1 * H + (size_t)k * H + n] : 0.f;
    W1t[o] = f2bf(v);
}

__global__ __launch_bounds__(256)
void convert_w2(const float* __restrict__ W2, unsigned short* __restrict__ W2t)
{   // [L][128][128] -> transposed bf16
    const int o = blockIdx.x * 256 + threadIdx.x;
    const int l = o / (H * H);
    const int r = o % (H * H);
    const int n = r / H;
    const int k = r % H;
    W2t[o] = f2bf(W2[(size_t)l * H * H + (size_t)k * H + n]);
}

__global__ __launch_bounds__(256)
void convert_wu(const float* __restrict__ Wu, unsigned short* __restrict__ Wut)
{   // [L][256][128] -> [L][128][256] bf16
    const int o = blockIdx.x * 256 + threadIdx.x;
    const int l = o / (H * 256);
    const int r = o % (H * 256);
    const int n = r / 256;
    const int k = r % 256;
    Wut[o] = f2bf(Wu[(size_t)l * 256 * H + (size_t)k * H + n]);
}

__global__ __launch_bounds__(256)
void convert_wp(const float* __restrict__ Wp, unsigned short* __restrict__ Wpt)
{   // [128][128] -> transposed bf16
    const int o = blockIdx.x * 256 + threadIdx.x;
    const int n = o / H;
    const int k = o % H;
    Wpt[o] = f2bf(Wp[(size_t)k * H + n]);
}

// edge_attr -> bf16 in sorted order
__global__ __launch_bounds__(256)
void convert_ea(const float* __restrict__ ea, const int* __restrict__ perm,
                unsigned short* __restrict__ eabf)
{
    const int o = blockIdx.x * 256 + threadIdx.x;
    const int p = o >> 3;
    const int j = (o & 7) * 2;
    const int pe = perm[p];
    const float2 v = *(const float2*)&ea[(size_t)pe * E_DIM + j];
    eabf[(size_t)p * E_DIM + j]     = f2bf(v.x);
    eabf[(size_t)p * E_DIM + j + 1] = f2bf(v.y);
}

// ---------------------------------------------------------------------------
// counting sort of edges by destination (i_idx); 3-phase parallel scan
// (R12's single-block serial scan was 100 us — the largest dispatch).
// ---------------------------------------------------------------------------
__global__ __launch_bounds__(256)
void hist_kernel(const int* __restrict__ ei, int* __restrict__ hist)
{
    const int e = blockIdx.x * 256 + threadIdx.x;
    if (e < N_EDGES) atomicAdd(&hist[ei[e]], 1);
}

// phase 1: per-block sums (coalesced + wave reduce)
__global__ __launch_bounds__(256)
void blocksum_kernel(const int* __restrict__ hist, int* __restrict__ bsum)
{
    __shared__ int red[4];
    const int t = threadIdx.x;
    const int idx = blockIdx.x * 256 + t;
    int v = (idx < N_NODES) ? hist[idx] : 0;
#pragma unroll
    for (int off = 32; off > 0; off >>= 1) v += __shfl_xor(v, off, 64);
    if ((t & 63) == 0) red[t >> 6] = v;
    __syncthreads();
    if (t == 0) bsum[blockIdx.x] = red[0] + red[1] + red[2] + red[3];
}

// phase 2: exclusive scan of NSB block sums (single tiny block)
__global__ __launch_bounds__(256)
void scan_bsum_kernel(const int* __restrict__ bsum, int* __restrict__ boff)
{
    __shared__ int s[256];
    const int t = threadIdx.x;
    const int v = (t < NSB) ? bsum[t] : 0;
    s[t] = v; __syncthreads();
    for (int off = 1; off < 256; off <<= 1) {
        const int u = (t >= off) ? s[t - off] : 0;
        __syncthreads();
        s[t] += u;
        __syncthreads();
    }
    if (t < NSB) boff[t] = s[t] - v;        // exclusive
}

// phase 3: per-chunk LDS scan + block offset -> exclusive cursor
__global__ __launch_bounds__(256)
void scan_final_kernel(const int* __restrict__ hist, const int* __restrict__ boff,
                       int* __restrict__ cursor)
{
    __shared__ int s[256];
    const int t = threadIdx.x;
    const int idx = blockIdx.x * 256 + t;
    const int v = (idx < N_NODES) ? hist[idx] : 0;
    s[t] = v; __syncthreads();
    for (int off = 1; off < 256; off <<= 1) {
        const int u = (t >= off) ? s[t - off] : 0;
        __syncthreads();
        s[t] += u;
        __syncthreads();
    }
    if (idx < N_NODES) cursor[idx] = boff[blockIdx.x] + s[t] - v;   // exclusive
}

__global__ __launch_bounds__(256)
void scatter_kernel(const int* __restrict__ ei, int* __restrict__ cursor,
                    int* __restrict__ i_s, int* __restrict__ j_s, int* __restrict__ perm)
{
    const int e = blockIdx.x * 256 + threadIdx.x;
    if (e < N_EDGES) {
        const int d = ei[e];
        const int p = atomicAdd(&cursor[d], 1);
        i_s[p] = d;
        j_s[p] = ei[N_EDGES + e];
        perm[p] = e;
    }
}

// ---------------------------------------------------------------------------
// proj (MFMA): hbf = bf16(x @ Wp + b)
// ---------------------------------------------------------------------------
__global__ __launch_bounds__(256)
void proj_mfma(const float* __restrict__ x, const unsigned short* __restrict__ Wpt,
               const float* __restrict__ b, unsigned short* __restrict__ hbf)
{
    __shared__ __align__(16) unsigned short A[MB][PS];
    const int tid = threadIdx.x;
    const int n0 = blockIdx.x * MB;
    const int wave = tid >> 6, lane = tid & 63, l15 = lane & 15, l4 = lane >> 4;
    const int colbase = wave * 32;

#pragma unroll
    for (int i = 0; i < 4; ++i) {
        const int f = tid + i * 256;
        const int row = f >> 5, c4 = f & 31;
        const int node = min(n0 + row, N_NODES - 1);
        const float4 v = *((const float4*)(x + (size_t)node * DIM_IN) + c4);
        unsigned short o[4] = { f2bf(v.x), f2bf(v.y), f2bf(v.z), f2bf(v.w) };
        *(uint2*)&A[row][c4 * 4] = *(const uint2*)o;
    }
    __syncthreads();

    f32x4 acc[2][2];
#pragma unroll
    for (int mt = 0; mt < 2; ++mt)
#pragma unroll
        for (int nt = 0; nt < 2; ++nt) acc[mt][nt] = (f32x4)0.f;

    for (int k = 0; k < DIM_IN; k += 32) {
        const s16x8 a0 = *(const s16x8*)&A[l15][k + l4 * 8];
        const s16x8 a1 = *(const s16x8*)&A[16 + l15][k + l4 * 8];
        const s16x8 b0 = *(const s16x8*)&Wpt[(size_t)(colbase + l15) * DIM_IN + k + l4 * 8];
        const s16x8 b1 = *(const s16x8*)&Wpt[(size_t)(colbase + 16 + l15) * DIM_IN + k + l4 * 8];
        acc[0][0] = __builtin_amdgcn_mfma_f32_16x16x32_bf16(a0, b0, acc[0][0], 0, 0, 0);
        acc[0][1] = __builtin_amdgcn_mfma_f32_16x16x32_bf16(a0, b1, acc[0][1], 0, 0, 0);
        acc[1][0] = __builtin_amdgcn_mfma_f32_16x16x32_bf16(a1, b0, acc[1][0], 0, 0, 0);
        acc[1][1] = __builtin_amdgcn_mfma_f32_16x16x32_bf16(a1, b1, acc[1][1], 0, 0, 0);
    }

    const float bi0 = b[colbase + l15], bi1 = b[colbase + 16 + l15];
#pragma unroll
    for (int mt = 0; mt < 2; ++mt)
#pragma unroll
        for (int r = 0; r < 4; ++r) {
            const int row = mt * 16 + l4 * 4 + r;
            const int n = n0 + row;
            if (n < N_NODES) {
                hbf[(size_t)n * H + colbase + l15]      = f2bf(acc[mt][0][r] + bi0);
                hbf[(size_t)n * H + colbase + 16 + l15] = f2bf(acc[mt][1][r] + bi1);
            }
        }
}

// ---------------------------------------------------------------------------
// premul: Pa = bf16(h @ W1a), Pb = bf16(h @ W1b)  — dense, coalesced.
// ---------------------------------------------------------------------------
__global__ __launch_bounds__(256)
void premul(const unsigned short* __restrict__ hbf,
            const unsigned short* __restrict__ W1t,
            unsigned short* __restrict__ Pa, unsigned short* __restrict__ Pb)
{
    __shared__ __align__(16) unsigned short A[MB][PS];
    const int tid = threadIdx.x;
    const int n0 = blockIdx.x * MB;
    const int wave = tid >> 6, lane = tid & 63, l15 = lane & 15, l4 = lane >> 4;
    const int colbase = wave * 32;

#pragma unroll
    for (int i = 0; i < 2; ++i) {
        const int f = tid + i * 256;
        const int row = f >> 4, c = f & 15;
        const int node = min(n0 + row, N_NODES - 1);
        const uint4 v = *((const uint4*)(hbf + (size_t)node * H) + c);
        *(uint4*)&A[row][c * 8] = v;
    }
    __syncthreads();

    f32x4 aa[2][2], ab[2][2];
#pragma unroll
    for (int mt = 0; mt < 2; ++mt)
#pragma unroll
        for (int nt = 0; nt < 2; ++nt) { aa[mt][nt] = (f32x4)0.f; ab[mt][nt] = (f32x4)0.f; }

#pragma unroll
    for (int kt = 0; kt < 4; ++kt) {
        const s16x8 a0 = *(const s16x8*)&A[l15][kt * 32 + l4 * 8];
        const s16x8 a1 = *(const s16x8*)&A[16 + l15][kt * 32 + l4 * 8];
        const s16x8 wa0 = *(const s16x8*)&W1t[(size_t)(colbase + l15) * K1P + kt * 32 + l4 * 8];
        const s16x8 wa1 = *(const s16x8*)&W1t[(size_t)(colbase + 16 + l15) * K1P + kt * 32 + l4 * 8];
        const s16x8 wb0 = *(const s16x8*)&W1t[(size_t)(colbase + l15) * K1P + 128 + kt * 32 + l4 * 8];
        const s16x8 wb1 = *(const s16x8*)&W1t[(size_t)(colbase + 16 + l15) * K1P + 128 + kt * 32 + l4 * 8];
        aa[0][0] = __builtin_amdgcn_mfma_f32_16x16x32_bf16(a0, wa0, aa[0][0], 0, 0, 0);
        aa[0][1] = __builtin_amdgcn_mfma_f32_16x16x32_bf16(a0, wa1, aa[0][1], 0, 0, 0);
        aa[1][0] = __builtin_amdgcn_mfma_f32_16x16x32_bf16(a1, wa0, aa[1][0], 0, 0, 0);
        aa[1][1] = __builtin_amdgcn_mfma_f32_16x16x32_bf16(a1, wa1, aa[1][1], 0, 0, 0);
        ab[0][0] = __builtin_amdgcn_mfma_f32_16x16x32_bf16(a0, wb0, ab[0][0], 0, 0, 0);
        ab[0][1] = __builtin_amdgcn_mfma_f32_16x16x32_bf16(a0, wb1, ab[0][1], 0, 0, 0);
        ab[1][0] = __builtin_amdgcn_mfma_f32_16x16x32_bf16(a1, wb0, ab[1][0], 0, 0, 0);
        ab[1][1] = __builtin_amdgcn_mfma_f32_16x16x32_bf16(a1, wb1, ab[1][1], 0, 0, 0);
    }

#pragma unroll
    for (int mt = 0; mt < 2; ++mt)
#pragma unroll
        for (int r = 0; r < 4; ++r) {
            const int row = mt * 16 + l4 * 4 + r;
            const int n = n0 + row;
            if (n < N_NODES) {
                Pa[(size_t)n * H + colbase + l15]      = f2bf(aa[mt][0][r]);
                Pa[(size_t)n * H + colbase + 16 + l15] = f2bf(aa[mt][1][r]);
                Pb[(size_t)n * H + colbase + l15]      = f2bf(ab[mt][0][r]);
                Pb[(size_t)n * H + colbase + 16 + l15] = f2bf(ab[mt][1][r]);
            }
        }
}

// ---------------------------------------------------------------------------
// edge kernel v2: no GEMM1. Per 32-edge tile: gather Pa[i]+Pb[j] (reg add ->
// Gsum LDS), e@W1c via single-ktile MFMA, hid = relu(eterm + Gsum + b1),
// GEMM2, pure-atomic 16-row segment reduce. 2 barriers/tile, reg prefetch.
// ---------------------------------------------------------------------------
__global__ __launch_bounds__(256, 4)
void edge_kernel(const unsigned short* __restrict__ Pa,
                 const unsigned short* __restrict__ Pb,
                 const unsigned short* __restrict__ eabf,  // [E][16] bf16, sorted
                 const int*   __restrict__ i_s,
                 const int*   __restrict__ j_s,
                 const unsigned short* __restrict__ W1t,   // [128][288] (W1c at k=256..287)
                 const float* __restrict__ b1,
                 const unsigned short* __restrict__ W2t,   // [128][128]
                 const float* __restrict__ b2,
                 float*       __restrict__ agg)
{
    __shared__ __align__(16) unsigned short Gsum[MB * GS];  // 8704 B
    __shared__ __align__(16) unsigned short Et[MB * ES];    // 2560 B
    __shared__ __align__(16) unsigned short Hid[MB * HS];   // 8704 B
    __shared__ __align__(16) unsigned short Mbf[MB * HS];   // 8704 B
    __shared__ int idxbuf[2][MB];                           //  256 B

    const int tid  = threadIdx.x;
    const int wave = tid >> 6;
    const int lane = tid & 63;
    const int l15  = lane & 15;
    const int l4   = lane >> 4;
    const int colbase = wave * 32;

    const int sl_e = tid >> 4;          // edge row for slot i: sl_e + i*16
    const int sl_c = tid & 15;          // uint4 chunk within row

    // weights in registers: W2 frags (32 VGPR) + W1c frags (8 VGPR)
    s16x8 w2f[2][4], w1cf[2];
#pragma unroll
    for (int kt = 0; kt < 4; ++kt) {
        w2f[0][kt] = *(const s16x8*)&W2t[(size_t)(colbase + l15) * H + kt * 32 + l4 * 8];
        w2f[1][kt] = *(const s16x8*)&W2t[(size_t)(colbase + 16 + l15) * H + kt * 32 + l4 * 8];
    }
    w1cf[0] = *(const s16x8*)&W1t[(size_t)(colbase + l15) * K1P + 256 + l4 * 8];
    w1cf[1] = *(const s16x8*)&W1t[(size_t)(colbase + 16 + l15) * K1P + 256 + l4 * 8];
    const float b1c0 = b1[colbase + l15], b1c1 = b1[colbase + 16 + l15];
    const float b2c0 = b2[colbase + l15], b2c1 = b2[colbase + 16 + l15];

    int t = blockIdx.x;
    if (t >= NT_E) return;

    // ---- prologue: stage tile t
    {
#pragma unroll
        for (int i = 0; i < 2; ++i) {
            const int e = sl_e + i * 16;
            const int ni = i_s[t * MB + e];
            const int nj = j_s[t * MB + e];
            const uint4 va = *((const uint4*)(Pa + (size_t)ni * H) + sl_c);
            const uint4 vb = *((const uint4*)(Pb + (size_t)nj * H) + sl_c);
            *(uint4*)&Gsum[e * GS + sl_c * 8] = addbf8(va, vb);
        }
        if (tid < 64) {
            const uint4 ve = *((const uint4*)eabf + (size_t)t * 64 + tid);
            *(uint4*)&Et[(tid >> 1) * ES + (tid & 1) * 8] = ve;
        } else if (tid < 128) {
            const int tt = tid - 64;
            const uint4 z = {0, 0, 0, 0};
            *(uint4*)&Et[(tt >> 1) * ES + 16 + (tt & 1) * 8] = z;   // pad stays zero
        }
        if (tid < MB) idxbuf[0][tid] = i_s[t * MB + tid];
    }
    __syncthreads();

    int p = 0;
    for (; t < NT_E; t += gridDim.x, p ^= 1) {
        const int t1 = t + gridDim.x;

        // ---- 1. prefetch next tile into registers
        uint4 pfa[2], pfb[2];
        uint4 pfe = {0, 0, 0, 0};
        int   pfi = 0;
        if (t1 < NT_E) {
#pragma unroll
            for (int i = 0; i < 2; ++i) {
                const int e = sl_e + i * 16;
                const int ni = i_s[t1 * MB + e];
                const int nj = j_s[t1 * MB + e];
                pfa[i] = *((const uint4*)(Pa + (size_t)ni * H) + sl_c);
                pfb[i] = *((const uint4*)(Pb + (size_t)nj * H) + sl_c);
            }
            if (tid < 64) pfe = *((const uint4*)eabf + (size_t)t1 * 64 + tid);
            if (tid < MB) pfi = i_s[t1 * MB + tid];
        }

        // ---- 2. e-term MFMA (single ktile, K=32 w/ zero pad)
        f32x4 acc[2][2];
#pragma unroll
        for (int mt = 0; mt < 2; ++mt)
#pragma unroll
            for (int nt = 0; nt < 2; ++nt) acc[mt][nt] = (f32x4)0.f;
        {
            const s16x8 a0 = *(const s16x8*)&Et[l15 * ES + l4 * 8];
            const s16x8 a1 = *(const s16x8*)&Et[(16 + l15) * ES + l4 * 8];
            acc[0][0] = __builtin_amdgcn_mfma_f32_16x16x32_bf16(a0, w1cf[0], acc[0][0], 0, 0, 0);
            acc[0][1] = __builtin_amdgcn_mfma_f32_16x16x32_bf16(a0, w1cf[1], acc[0][1], 0, 0, 0);
            acc[1][0] = __builtin_amdgcn_mfma_f32_16x16x32_bf16(a1, w1cf[0], acc[1][0], 0, 0, 0);
            acc[1][1] = __builtin_amdgcn_mfma_f32_16x16x32_bf16(a1, w1cf[1], acc[1][1], 0, 0, 0);
        }

        // ---- 3. hid = relu(eterm + Gsum + b1) -> Hid
#pragma unroll
        for (int mt = 0; mt < 2; ++mt)
#pragma unroll
            for (int r = 0; r < 4; ++r) {
                const int row = mt * 16 + l4 * 4 + r;
                const float g0 = bf2f(Gsum[row * GS + colbase + l15]);
                const float g1 = bf2f(Gsum[row * GS + colbase + 16 + l15]);
                Hid[row * HS + colbase + l15]      = f2bf(fmaxf(acc[mt][0][r] + g0 + b1c0, 0.f));
                Hid[row * HS + colbase + 16 + l15] = f2bf(fmaxf(acc[mt][1][r] + g1 + b1c1, 0.f));
            }
        __syncthreads();             // barrier A: Gsum/Et reads done, Hid ready

        // ---- 4. drain prefetch: add Pa+Pb -> Gsum; Et; idxbuf[p^1]
        if (t1 < NT_E) {
#pragma unroll
            for (int i = 0; i < 2; ++i) {
                const int e = sl_e + i * 16;
                *(uint4*)&Gsum[e * GS + sl_c * 8] = addbf8(pfa[i], pfb[i]);
            }
            if (tid < 64)
                *(uint4*)&Et[(tid >> 1) * ES + (tid & 1) * 8] = pfe;
            if (tid < MB) idxbuf[p ^ 1][tid] = pfi;
        }

        // ---- 5. GEMM2: Hid[32x128] x W2 -> acc
#pragma unroll
        for (int mt = 0; mt < 2; ++mt)
#pragma unroll
            for (int nt = 0; nt < 2; ++nt) acc[mt][nt] = (f32x4)0.f;

#pragma unroll
        for (int kt = 0; kt < 4; ++kt) {
            const s16x8 a0 = *(const s16x8*)&Hid[l15 * HS + kt * 32 + l4 * 8];
            const s16x8 a1 = *(const s16x8*)&Hid[(16 + l15) * HS + kt * 32 + l4 * 8];
            acc[0][0] = __builtin_amdgcn_mfma_f32_16x16x32_bf16(a0, w2f[0][kt], acc[0][0], 0, 0, 0);
            acc[0][1] = __builtin_amdgcn_mfma_f32_16x16x32_bf16(a0, w2f[1][kt], acc[0][1], 0, 0, 0);
            acc[1][0] = __builtin_amdgcn_mfma_f32_16x16x32_bf16(a1, w2f[0][kt], acc[1][0], 0, 0, 0);
            acc[1][1] = __builtin_amdgcn_mfma_f32_16x16x32_bf16(a1, w2f[1][kt], acc[1][1], 0, 0, 0);
        }

        // ---- 6. m = relu(acc+b2) -> Mbf
#pragma unroll
        for (int mt = 0; mt < 2; ++mt)
#pragma unroll
            for (int r = 0; r < 4; ++r) {
                const int row = mt * 16 + l4 * 4 + r;
                Mbf[row * HS + colbase + l15]      = f2bf(fmaxf(acc[mt][0][r] + b2c0, 0.f));
                Mbf[row * HS + colbase + 16 + l15] = f2bf(fmaxf(acc[mt][1][r] + b2c1, 0.f));
            }
        __syncthreads();             // barrier B: Mbf ready, next tile staged

        // ---- 7. 16-row segment reduce, pure atomics (R6-proven)
        {
            const int* idxp = idxbuf[p];
            const int c    = tid & 127;
            const int half = tid >> 7;
            int cur = idxp[half * 16];
            float s = 0.f;
            for (int r = half * 16; r < half * 16 + 16; ++r) {
                const int d = idxp[r];
                if (d != cur) {
                    atomicAdd(&agg[(size_t)cur * H + c], s);
                    s = 0.f; cur = d;
                }
                s += bf2f(Mbf[r * HS + c]);
            }
            atomicAdd(&agg[(size_t)cur * H + c], s);
        }
        // reduce(k) reads Mbf/idxbuf[p]; next writers gated by barrier A(k+1).
    }
}

// ---------------------------------------------------------------------------
// node update (MFMA, 64 rows/block): out = relu([h,agg]Wu+b);
// hbf = bf16(LN(out+h)); agg rows re-zeroed for next layer (replaces memset).
// ---------------------------------------------------------------------------
__global__ __launch_bounds__(256, 3)
void update_mfma(unsigned short* __restrict__ hbf, float* __restrict__ agg,
                 const unsigned short* __restrict__ Wut, const float* __restrict__ b,
                 const float* __restrict__ g, const float* __restrict__ bln)
{
    __shared__ __align__(16) unsigned short A[UMB][US];  // 33792 B
    float* Afp = (float*)&A[0][0];                       // [64][FPS] overlay

    const int tid = threadIdx.x;
    const int n0 = blockIdx.x * UMB;
    const int wave = tid >> 6, lane = tid & 63, l15 = lane & 15, l4 = lane >> 4;
    const int colbase = wave * 32;

    s16x8 bf0[8], bf1[8];
#pragma unroll
    for (int kt = 0; kt < 8; ++kt) {
        bf0[kt] = *(const s16x8*)&Wut[(size_t)(colbase + l15) * 256 + kt * 32 + l4 * 8];
        bf1[kt] = *(const s16x8*)&Wut[(size_t)(colbase + 16 + l15) * 256 + kt * 32 + l4 * 8];
    }

#pragma unroll
    for (int i = 0; i < 4; ++i) {
        const int f = tid + i * 256;
        const int row = f >> 4, c = f & 15;
        const int node = min(n0 + row, N_NODES - 1);
        const uint4 v = *((const uint4*)(hbf + (size_t)node * H) + c);
        *(uint4*)&A[row][c * 8] = v;
    }
#pragma unroll
    for (int i = 0; i < 8; ++i) {
        const int f = tid + i * 256;
        const int row = f >> 5, c4 = f & 31;
        const int node = min(n0 + row, N_NODES - 1);
        float4* ap = (float4*)(agg + (size_t)node * H) + c4;
        const float4 v = *ap;
        if (n0 + row < N_NODES) {
            const float4 z = {0.f, 0.f, 0.f, 0.f};
            *ap = z;
        }
        unsigned short o[4] = { f2bf(v.x), f2bf(v.y), f2bf(v.z), f2bf(v.w) };
        *(uint2*)&A[row][128 + c4 * 4] = *(const uint2*)o;
    }
    __syncthreads();

    f32x4 acc[4][2];
#pragma unroll
    for (int mt = 0; mt < 4; ++mt) { acc[mt][0] = (f32x4)0.f; acc[mt][1] = (f32x4)0.f; }

#pragma unroll
    for (int kt = 0; kt < 8; ++kt) {
#pragma unroll
        for (int mt = 0; mt < 4; ++mt) {
            const s16x8 a = *(const s16x8*)&A[mt * 16 + l15][kt * 32 + l4 * 8];
            acc[mt][0] = __builtin_amdgcn_mfma_f32_16x16x32_bf16(a, bf0[kt], acc[mt][0], 0, 0, 0);
            acc[mt][1] = __builtin_amdgcn_mfma_f32_16x16x32_bf16(a, bf1[kt], acc[mt][1], 0, 0, 0);
        }
    }
    __syncthreads();

    {
        const float bi0 = b[colbase + l15], bi1 = b[colbase + 16 + l15];
#pragma unroll
        for (int mt = 0; mt < 4; ++mt)
#pragma unroll
            for (int r = 0; r < 4; ++r) {
                const int row = mt * 16 + l4 * 4 + r;
                Afp[row * FPS + colbase + l15]      = fmaxf(acc[mt][0][r] + bi0, 0.f);
                Afp[row * FPS + colbase + 16 + l15] = fmaxf(acc[mt][1][r] + bi1, 0.f);
            }
    }
    __syncthreads();

    const float g0 = g[lane],   g1 = g[64 + lane];
    const float l0 = bln[lane], l1 = bln[64 + lane];
    for (int q = 0; q < 16; ++q) {
        const int row = wave * 16 + q;
        const int n = n0 + row;
        if (n >= N_NODES) break;
        const float hr0 = bf2f(hbf[(size_t)n * H + lane]);
        const float hr1 = bf2f(hbf[(size_t)n * H + 64 + lane]);
        float v0 = Afp[row * FPS + lane]      + hr0;
        float v1 = Afp[row * FPS + 64 + lane] + hr1;
        float s = v0 + v1;
#pragma unroll
        for (int off = 32; off > 0; off >>= 1) s += __shfl_xor(s, off, 64);
        const float mu = s * (1.f / 128.f);
        const float d0 = v0 - mu, d1 = v1 - mu;
        float vs = d0 * d0 + d1 * d1;
#pragma unroll
        for (int off = 32; off > 0; off >>= 1) vs += __shfl_xor(vs, off, 64);
        const float inv = rsqrtf(vs * (1.f / 128.f) + 1e-5f);
        hbf[(size_t)n * H + lane]      = f2bf(d0 * inv * g0 + l0);
        hbf[(size_t)n * H + 64 + lane] = f2bf(d1 * inv * g1 + l1);
    }
}

// ---------------------------------------------------------------------------
// final: out[c] = mean_n LN(hbf[n]; g,b)[c]
// ---------------------------------------------------------------------------
__global__ __launch_bounds__(256)
void final_kernel(const unsigned short* __restrict__ hbf,
                  const float* __restrict__ g, const float* __restrict__ b,
                  float* __restrict__ out)
{
    __shared__ float red[4][128];
    const int tid = threadIdx.x;
    const int wave = tid >> 6, lane = tid & 63;
    const float g0 = g[lane], g1 = g[64 + lane];
    const float b0 = b[lane], b1 = b[64 + lane];
    float a0 = 0.f, a1 = 0.f;

    for (int n = blockIdx.x * 4 + wave; n < N_NODES; n += gridDim.x * 4) {
        const float v0 = bf2f(hbf[(size_t)n * H + lane]);
        const float v1 = bf2f(hbf[(size_t)n * H + 64 + lane]);
        float s = v0 + v1;
#pragma unroll
        for (int off = 32; off > 0; off >>= 1) s += __shfl_xor(s, off, 64);
        const float mu = s * (1.f / 128.f);
        const float d0 = v0 - mu, d1 = v1 - mu;
        float vs = d0 * d0 + d1 * d1;
#pragma unroll
        for (int off = 32; off > 0; off >>= 1) vs += __shfl_xor(vs, off, 64);
        const float inv = rsqrtf(vs * (1.f / 128.f) + 1e-5f);
        a0 += d0 * inv * g0 + b0;
        a1 += d1 * inv * g1 + b1;
    }
    red[wave][lane]      = a0;
    red[wave][64 + lane] = a1;
    __syncthreads();
    if (wave == 0) {
        const float s0 = red[0][lane] + red[1][lane] + red[2][lane] + red[3][lane];
        const float s1 = red[0][64 + lane] + red[1][64 + lane] + red[2][64 + lane] + red[3][64 + lane];
        atomicAdd(&out[lane],      s0 * (1.f / N_NODES));
        atomicAdd(&out[64 + lane], s1 * (1.f / N_NODES));
    }
}

// ---------------------------------------------------------------------------
extern "C" void kernel_launch(void* const* d_in, const int* in_sizes, int n_in,
                              void* d_out, int out_size, void* d_ws, size_t ws_size,
                              hipStream_t stream)
{
    const float* x         = (const float*)d_in[0];
    const float* edge_attr = (const float*)d_in[1];
    const int*   edge_idx  = (const int*)  d_in[2];
    const float* proj_W    = (const float*)d_in[3];
    const float* proj_b    = (const float*)d_in[4];
    const float* msg_W1    = (const float*)d_in[5];
    const float* msg_b1    = (const float*)d_in[6];
    const float* msg_W2    = (const float*)d_in[7];
    const float* msg_b2    = (const float*)d_in[8];
    const float* upd_W     = (const float*)d_in[9];
    const float* upd_b     = (const float*)d_in[10];
    const float* ln_g      = (const float*)d_in[11];
    const float* ln_b      = (const float*)d_in[12];
    const float* out_g     = (const float*)d_in[13];
    const float* out_b     = (const float*)d_in[14];
    float* out = (float*)d_out;

    char* w = (char*)d_ws;
    float* agg = (float*)w;                   w += (size_t)N_NODES * H * 4;
    unsigned short* hbf  = (unsigned short*)w; w += (size_t)N_NODES * H * 2;
    unsigned short* Pa   = (unsigned short*)w; w += (size_t)N_NODES * H * 2;
    unsigned short* Pb   = (unsigned short*)w; w += (size_t)N_NODES * H * 2;
    unsigned short* eabf = (unsigned short*)w; w += (size_t)N_EDGES * E_DIM * 2;
    unsigned short* W1t  = (unsigned short*)w; w += (size_t)NLAYERS * H * K1P * 2;
    unsigned short* W2t  = (unsigned short*)w; w += (size_t)NLAYERS * H * H * 2;
    unsigned short* Wut  = (unsigned short*)w; w += (size_t)NLAYERS * H * 256 * 2;
    unsigned short* Wpt  = (unsigned short*)w; w += (size_t)H * DIM_IN * 2;
    int* hist   = (int*)w;                    w += (size_t)N_NODES * 4;
    int* cursor = (int*)w;                    w += (size_t)N_NODES * 4;
    int* bsum   = (int*)w;                    w += (size_t)256 * 4;
    int* boff   = (int*)w;                    w += (size_t)256 * 4;
    int* i_s    = (int*)w;                    w += (size_t)N_EDGES * 4;
    int* j_s    = (int*)w;                    w += (size_t)N_EDGES * 4;
    int* perm   = (int*)w;                    w += (size_t)N_EDGES * 4;

    convert_w1<<<(NLAYERS * H * K1P) / 256, 256, 0, stream>>>(msg_W1, W1t);
    convert_w2<<<(NLAYERS * H * H) / 256, 256, 0, stream>>>(msg_W2, W2t);
    convert_wu<<<(NLAYERS * H * 256) / 256, 256, 0, stream>>>(upd_W, Wut);
    convert_wp<<<(H * DIM_IN) / 256, 256, 0, stream>>>(proj_W, Wpt);

    hipMemsetAsync(hist, 0, (size_t)N_NODES * 4, stream);
    hipMemsetAsync(agg, 0, (size_t)N_NODES * H * sizeof(float), stream);  // once; update re-zeroes
    hist_kernel<<<(N_EDGES + 255) / 256, 256, 0, stream>>>(edge_idx, hist);
    blocksum_kernel<<<NSB, 256, 0, stream>>>(hist, bsum);
    scan_bsum_kernel<<<1, 256, 0, stream>>>(bsum, boff);
    scan_final_kernel<<<NSB, 256, 0, stream>>>(hist, boff, cursor);
    scatter_kernel<<<(N_EDGES + 255) / 256, 256, 0, stream>>>(edge_idx, cursor, i_s, j_s, perm);
    convert_ea<<<(N_EDGES * 8) / 256, 256, 0, stream>>>(edge_attr, perm, eabf);

    const int nblk = (N_NODES + MB - 1) / MB;
    proj_mfma<<<nblk, 256, 0, stream>>>(x, Wpt, proj_b, hbf);

    const int ublk = (N_NODES + UMB - 1) / UMB;
    for (int l = 0; l < NLAYERS; ++l) {
        premul<<<nblk, 256, 0, stream>>>(hbf, W1t + (size_t)l * H * K1P, Pa, Pb);
        edge_kernel<<<1024, 256, 0, stream>>>(
            Pa, Pb, eabf, i_s, j_s,
            W1t + (size_t)l * H * K1P, msg_b1 + (size_t)l * H,
            W2t + (size_t)l * H * H,   msg_b2 + (size_t)l * H, agg);
        update_mfma<<<ublk, 256, 0, stream>>>(
            hbf, agg, Wut + (size_t)l * H * 256, upd_b + (size_t)l * H,
            ln_g + (size_t)l * H, ln_b + (size_t)l * H);
    }

    hipMemsetAsync(out, 0, H * sizeof(float), stream);
    final_kernel<<<256, 256, 0, stream>>>(hbf, out_g, out_b, out);
}